// Round 1
// baseline (5898.777 us; speedup 1.0000x reference)
//
#include <hip/hip_runtime.h>
#include <hip/hip_bf16.h>
#include <math.h>

#define DEV __device__ __forceinline__

constexpr int D96 = 96;
constexpr int N96 = D96 * D96 * D96;      // 884736
constexpr int D48 = 48;
constexpr int N48 = D48 * D48 * D48;      // 110592

// Gaussian kernel (sigma=1, radius=3), normalized
#define GW0 0.3990502796524549f
#define GW1 0.2420362293761143f
#define GW2 0.05400558262251696f
#define GW3 0.004433048175243745f

DEV int clampi(int v, int lo, int hi) { return v < lo ? lo : (v > hi ? hi : v); }

DEV float toF(float v) { return v; }
DEV float toF(__hip_bfloat16 v) { return __bfloat162float(v); }
template <typename T> DEV T frF(float v);
template <> DEV float frF<float>(float v) { return v; }
template <> DEV __hip_bfloat16 frF<__hip_bfloat16>(float v) { return __float2bfloat16(v); }

// ---------------- resize 96 -> 48, trilinear antialias (4-tap 1,3,3,1 /8, edge renorm)
__global__ void k_downsample2x(const float* __restrict__ src, float* __restrict__ dst)
{
    int idx = blockIdx.x * blockDim.x + threadIdx.x;
    if (idx >= N48) return;
    int x = idx % D48, y = (idx / D48) % D48, z = idx / (D48 * D48);

    float wz[4], wy[4], wx[4];
    int jz[4], jy[4], jx[4];
    auto mk = [](int i, float* w, int* j) {
        const float base[4] = {0.125f, 0.375f, 0.375f, 0.125f};
        float s = 0.f;
        #pragma unroll
        for (int t = 0; t < 4; ++t) {
            int jj = 2 * i - 1 + t;
            bool v = (jj >= 0) && (jj < D96);
            j[t] = v ? jj : 0;
            w[t] = v ? base[t] : 0.f;
            s += w[t];
        }
        float inv = 1.f / s;
        #pragma unroll
        for (int t = 0; t < 4; ++t) w[t] *= inv;
    };
    mk(z, wz, jz); mk(y, wy, jy); mk(x, wx, jx);

    float acc = 0.f;
    #pragma unroll
    for (int a = 0; a < 4; ++a) {
        #pragma unroll
        for (int b = 0; b < 4; ++b) {
            float wab = wz[a] * wy[b];
            int rowoff = (jz[a] * D96 + jy[b]) * D96;
            #pragma unroll
            for (int c = 0; c < 4; ++c)
                acc += wab * wx[c] * src[rowoff + jx[c]];
        }
    }
    dst[idx] = acc;
}

// ---------------- vf upsample 48 -> 96 (trilinear, edge renorm) with *2 magnitude scale
__global__ void k_upsample_vf(const float* __restrict__ src, float* __restrict__ dst)
{
    int idx = blockIdx.x * blockDim.x + threadIdx.x;
    if (idx >= 3 * N96) return;
    int c = idx / N96;
    int s = idx - c * N96;
    int x = s % D96, y = (s / D96) % D96, z = s / (D96 * D96);

    auto mk = [](int i, int* j, float* w) {
        int k = i >> 1;
        if ((i & 1) == 0) { j[0] = k - 1; w[0] = 0.25f; j[1] = k; w[1] = 0.75f; }
        else              { j[0] = k;     w[0] = 0.75f; j[1] = k + 1; w[1] = 0.25f; }
        float sum = 0.f;
        #pragma unroll
        for (int t = 0; t < 2; ++t) {
            bool v = (j[t] >= 0) && (j[t] < D48);
            if (!v) { w[t] = 0.f; j[t] = 0; }
            sum += w[t];
        }
        float inv = 1.f / sum;
        w[0] *= inv; w[1] *= inv;
    };
    int jz[2], jy[2], jx[2]; float wz[2], wy[2], wx[2];
    mk(z, jz, wz); mk(y, jy, wy); mk(x, jx, wx);

    const float* p = src + (size_t)c * N48;
    float acc = 0.f;
    #pragma unroll
    for (int a = 0; a < 2; ++a)
        #pragma unroll
        for (int b = 0; b < 2; ++b) {
            float wab = wz[a] * wy[b];
            int rowoff = (jz[a] * D48 + jy[b]) * D48;
            acc += wab * (wx[0] * p[rowoff + jx[0]] + wx[1] * p[rowoff + jx[1]]);
        }
    dst[idx] = 2.f * acc;   // per-axis magnitude scale 96/48
}

// ---------------- trilinear warp, mode='nearest' (clamped indices)
__global__ void k_warp(const float* __restrict__ img, const float* __restrict__ vf,
                       float* __restrict__ out, int D)
{
    int N = D * D * D;
    int idx = blockIdx.x * blockDim.x + threadIdx.x;
    if (idx >= N) return;
    int x = idx % D, y = (idx / D) % D, z = idx / (D * D);
    float cz = z + vf[idx], cy = y + vf[N + idx], cx = x + vf[2 * N + idx];
    float fz = floorf(cz), fy = floorf(cy), fx = floorf(cx);
    float wz = cz - fz, wy = cy - fy, wx = cx - fx;
    int z0 = clampi((int)fz, 0, D - 1), z1 = clampi((int)fz + 1, 0, D - 1);
    int y0 = clampi((int)fy, 0, D - 1), y1 = clampi((int)fy + 1, 0, D - 1);
    int x0 = clampi((int)fx, 0, D - 1), x1 = clampi((int)fx + 1, 0, D - 1);
    float v000 = img[(z0 * D + y0) * D + x0], v001 = img[(z0 * D + y0) * D + x1];
    float v010 = img[(z0 * D + y1) * D + x0], v011 = img[(z0 * D + y1) * D + x1];
    float v100 = img[(z1 * D + y0) * D + x0], v101 = img[(z1 * D + y0) * D + x1];
    float v110 = img[(z1 * D + y1) * D + x0], v111 = img[(z1 * D + y1) * D + x1];
    float c00 = v000 + wx * (v001 - v000);
    float c01 = v010 + wx * (v011 - v010);
    float c10 = v100 + wx * (v101 - v100);
    float c11 = v110 + wx * (v111 - v110);
    float c0 = c00 + wy * (c01 - c00);
    float c1 = c10 + wy * (c11 - c10);
    out[idx] = c0 + wz * (c1 - c0);
}

// ---------------- demon forces + vf update (in place)
__global__ void k_forces(const float* __restrict__ warped, const float* __restrict__ fixed,
                         const float* __restrict__ mask, const float* __restrict__ spacing,
                         float* __restrict__ vf, int D, int maskD, float tau)
{
    int N = D * D * D;
    int idx = blockIdx.x * blockDim.x + threadIdx.x;
    if (idx >= N) return;
    int x = idx % D, y = (idx / D) % D, z = idx / (D * D);
    float w0 = warped[idx];
    float diff = w0 - fixed[idx];
    int sZ = D * D, sY = D;
    float gz = (z == 0) ? warped[idx + sZ] - w0 : (z == D - 1) ? w0 - warped[idx - sZ]
               : 0.5f * (warped[idx + sZ] - warped[idx - sZ]);
    float gy = (y == 0) ? warped[idx + sY] - w0 : (y == D - 1) ? w0 - warped[idx - sY]
               : 0.5f * (warped[idx + sY] - warped[idx - sY]);
    float gx = (x == 0) ? warped[idx + 1] - w0 : (x == D - 1) ? w0 - warped[idx - 1]
               : 0.5f * (warped[idx + 1] - warped[idx - 1]);
    gz /= spacing[0]; gy /= spacing[1]; gx /= spacing[2];
    float denom = gz * gz + gy * gy + gx * gx + diff * diff;
    float m;
    if (D == maskD) m = mask[idx];
    else {
        float r = (float)maskD / (float)D;
        int mz = clampi((int)((z + 0.5f) * r), 0, maskD - 1);
        int my = clampi((int)((y + 0.5f) * r), 0, maskD - 1);
        int mx = clampi((int)((x + 0.5f) * r), 0, maskD - 1);
        m = mask[(mz * maskD + my) * maskD + mx];
    }
    if (denom > 1e-9f) {
        float sc = tau * diff / denom * m;
        vf[idx]         += sc * gz;
        vf[N + idx]     += sc * gy;
        vf[2 * N + idx] += sc * gx;
    }
}

// ---------------- separable 7-tap Gaussian along one axis, zero padding, nch channels
__global__ void k_smooth(const float* __restrict__ src, float* __restrict__ dst,
                         int D, int axis, int nch)
{
    int N = D * D * D;
    int total = nch * N;
    int idx = blockIdx.x * blockDim.x + threadIdx.x;
    if (idx >= total) return;
    int s = idx % N;
    int x = s % D, y = (s / D) % D, z = s / (D * D);
    int a = (axis == 0) ? z : (axis == 1) ? y : x;
    int stride = (axis == 0) ? D * D : (axis == 1) ? D : 1;
    const float w[4] = {GW0, GW1, GW2, GW3};
    float acc = w[0] * src[idx];
    #pragma unroll
    for (int t = 1; t <= 3; ++t) {
        if (a - t >= 0) acc += w[t] * src[idx - t * stride];
        if (a + t < D)  acc += w[t] * src[idx + t * stride];
    }
    dst[idx] = acc;
}

// ---------------- pack CNN input: [vf0,vf1,vf2, image*mask, warped]
__global__ void k_pack(const float* __restrict__ vf, const float* __restrict__ image,
                       const float* __restrict__ mask, const float* __restrict__ warped,
                       float* __restrict__ xin)
{
    int idx = blockIdx.x * blockDim.x + threadIdx.x;
    if (idx >= N96) return;
    xin[idx]           = vf[idx];
    xin[N96 + idx]     = vf[N96 + idx];
    xin[2 * N96 + idx] = vf[2 * N96 + idx];
    xin[3 * N96 + idx] = image[idx] * mask[idx];
    xin[4 * N96 + idx] = warped[idx];
}

// ---------------- direct 3x3x3 conv, SAME, 8^3 tile in LDS, CPT output chans/thread
template <int CIN, int CPT, typename TIN, typename TOUT>
__global__ __launch_bounds__(512)
void k_conv3(const TIN* __restrict__ in, const float* __restrict__ wgt,
             const float* __restrict__ bias, TOUT* __restrict__ out)
{
    const int TPD = D96 / 8; // 12
    __shared__ float tile[1000]; // 10x10x10
    int t = blockIdx.x;
    int tx = t % TPD, ty = (t / TPD) % TPD, tz = t / (TPD * TPD);
    int coutBase = blockIdx.y * CPT;
    int tid = threadIdx.x;
    int lx = tid & 7, ly = (tid >> 3) & 7, lz = tid >> 6;
    int gx = tx * 8 + lx, gy = ty * 8 + ly, gz = tz * 8 + lz;
    int bz = tz * 8 - 1, by = ty * 8 - 1, bx = tx * 8 - 1;

    float acc[CPT];
    #pragma unroll
    for (int c = 0; c < CPT; ++c) acc[c] = 0.f;

    for (int ci = 0; ci < CIN; ++ci) {
        for (int l = tid; l < 1000; l += 512) {
            int sx = l % 10, sy = (l / 10) % 10, sz = l / 100;
            int az = bz + sz, ay = by + sy, ax = bx + sx;
            float v = 0.f;
            if ((unsigned)az < (unsigned)D96 && (unsigned)ay < (unsigned)D96 &&
                (unsigned)ax < (unsigned)D96)
                v = toF(in[(size_t)ci * N96 + (az * D96 + ay) * D96 + ax]);
            tile[l] = v;
        }
        __syncthreads();
        const float* wp = wgt + ((size_t)coutBase * CIN + ci) * 27;
        #pragma unroll
        for (int kz = 0; kz < 3; ++kz)
            #pragma unroll
            for (int ky = 0; ky < 3; ++ky)
                #pragma unroll
                for (int kx = 0; kx < 3; ++kx) {
                    float v = tile[((lz + kz) * 10 + (ly + ky)) * 10 + lx + kx];
                    const int k = (kz * 3 + ky) * 3 + kx;
                    #pragma unroll
                    for (int c = 0; c < CPT; ++c)
                        acc[c] = fmaf(v, wp[(size_t)c * CIN * 27 + k], acc[c]);
                }
        __syncthreads();
    }
    int vox = (gz * D96 + gy) * D96 + gx;
    #pragma unroll
    for (int c = 0; c < CPT; ++c) {
        float b = bias ? bias[coutBase + c] : 0.f;
        out[(size_t)(coutBase + c) * N96 + vox] = frF<TOUT>(acc[c] + b);
    }
}

// ---------------- instance-norm stats: stage 1 (per-block partials, deterministic)
template <typename T>
__global__ void k_stats1(const T* __restrict__ x, float* __restrict__ part, int N)
{
    int c = blockIdx.y;
    const T* p = x + (size_t)c * N;
    float s = 0.f, s2 = 0.f;
    for (int i = blockIdx.x * blockDim.x + threadIdx.x; i < N; i += gridDim.x * blockDim.x) {
        float v = toF(p[i]);
        s += v; s2 += v * v;
    }
    #pragma unroll
    for (int o = 32; o > 0; o >>= 1) { s += __shfl_down(s, o); s2 += __shfl_down(s2, o); }
    __shared__ float a[8], b[8];
    int lane = threadIdx.x & 63, wid = threadIdx.x >> 6;
    if (lane == 0) { a[wid] = s; b[wid] = s2; }
    __syncthreads();
    if (threadIdx.x == 0) {
        float ss = 0.f, qq = 0.f;
        #pragma unroll
        for (int i = 0; i < 8; ++i) { ss += a[i]; qq += b[i]; }
        part[((size_t)c * gridDim.x + blockIdx.x) * 2]     = ss;
        part[((size_t)c * gridDim.x + blockIdx.x) * 2 + 1] = qq;
    }
}

// stage 2: reduce 256 partials/channel -> mean + inv_std
__global__ void k_stats_reduce(const float* __restrict__ part, float* __restrict__ stats,
                               int G, int N)
{
    int c = blockIdx.x;
    int t = threadIdx.x;
    float s = 0.f, s2 = 0.f;
    for (int i = t; i < G; i += blockDim.x) {
        s  += part[((size_t)c * G + i) * 2];
        s2 += part[((size_t)c * G + i) * 2 + 1];
    }
    #pragma unroll
    for (int o = 32; o > 0; o >>= 1) { s += __shfl_down(s, o); s2 += __shfl_down(s2, o); }
    __shared__ float a[4], b[4];
    int lane = t & 63, wid = t >> 6;
    if (lane == 0) { a[wid] = s; b[wid] = s2; }
    __syncthreads();
    if (t == 0) {
        float ss = a[0] + a[1] + a[2] + a[3];
        float qq = b[0] + b[1] + b[2] + b[3];
        float mean = ss / (float)N;
        float var = qq / (float)N - mean * mean;
        stats[2 * c] = mean;
        stats[2 * c + 1] = rsqrtf(var + 1e-5f);
    }
}

// ---------------- (x - mean) * inv, then mish, in place
template <typename T>
__global__ void k_norm_mish(T* __restrict__ x, const float* __restrict__ stats)
{
    int c = blockIdx.y;
    float mean = stats[2 * c], inv = stats[2 * c + 1];
    int i = blockIdx.x * blockDim.x + threadIdx.x;
    if (i >= N96) return;
    T* p = x + (size_t)c * N96;
    float v = (toF(p[i]) - mean) * inv;
    float sp = (v > 20.f) ? v : log1pf(expf(v));
    p[i] = frF<T>(v * tanhf(sp));
}

__global__ void k_add3(float* __restrict__ dst, const float* __restrict__ src)
{
    int idx = blockIdx.x * blockDim.x + threadIdx.x;
    if (idx >= 3 * N96) return;
    dst[idx] += src[idx];
}

__global__ void k_copy(const float* __restrict__ src, float* __restrict__ dst, int n)
{
    int idx = blockIdx.x * blockDim.x + threadIdx.x;
    if (idx >= n) return;
    dst[idx] = src[idx];
}

extern "C" void kernel_launch(void* const* d_in, const int* in_sizes, int n_in,
                              void* d_out, int out_size, void* d_ws, size_t ws_size,
                              hipStream_t stream)
{
    const float* image   = (const float*)d_in[0];
    const float* mask    = (const float*)d_in[1];
    const float* moving  = (const float*)d_in[2];
    const float* spacing = (const float*)d_in[3];
    const float* w1 = (const float*)d_in[4];
    const float* w2 = (const float*)d_in[5];
    const float* w3 = (const float*)d_in[6];
    const float* w4 = (const float*)d_in[7];
    const float* b4 = (const float*)d_in[8];
    float* out = (float*)d_out;

    char* ws = (char*)d_ws;
    size_t off = 0;
    auto alloc = [&](size_t bytes) -> char* {
        char* p = ws + off;
        off += (bytes + 255) & ~(size_t)255;
        return p;
    };
    float* f48   = (float*)alloc((size_t)N48 * 4);
    float* mv48  = (float*)alloc((size_t)N48 * 4);
    float* vfA48 = (float*)alloc((size_t)3 * N48 * 4);
    float* vfB48 = (float*)alloc((size_t)3 * N48 * 4);
    float* wrp48 = (float*)alloc((size_t)N48 * 4);
    float* vfA96 = (float*)alloc((size_t)3 * N96 * 4);
    float* vfB96 = (float*)alloc((size_t)3 * N96 * 4);
    float* vfC96 = (float*)alloc((size_t)3 * N96 * 4);
    float* wrp96 = (float*)alloc((size_t)N96 * 4);
    float* xin   = (float*)alloc((size_t)5 * N96 * 4);
    float* part  = (float*)alloc((size_t)64 * 256 * 2 * 4);
    float* stats = (float*)alloc((size_t)64 * 2 * 4);
    __hip_bfloat16* y1 = (__hip_bfloat16*)alloc((size_t)32 * N96 * 2);
    __hip_bfloat16* y2 = (__hip_bfloat16*)alloc((size_t)64 * N96 * 2);

    const int B = 256;
    const int g48  = (N48 + B - 1) / B;
    const int g48c = (3 * N48 + B - 1) / B;
    const int g96  = (N96 + B - 1) / B;
    const int g96c = (3 * N96 + B - 1) / B;

    // ---- Level 0 (48^3) ----
    k_downsample2x<<<g48, B, 0, stream>>>(image, f48);
    k_downsample2x<<<g48, B, 0, stream>>>(moving, mv48);
    hipMemsetAsync(vfA48, 0, (size_t)3 * N48 * 4, stream);
    float* cur = vfA48; float* oth = vfB48;
    for (int it = 0; it < 2; ++it) {
        k_warp<<<g48, B, 0, stream>>>(mv48, cur, wrp48, D48);
        k_forces<<<g48, B, 0, stream>>>(wrp48, f48, mask, spacing, cur, D48, D96, 2.0f);
        k_smooth<<<g48c, B, 0, stream>>>(cur, oth, D48, 0, 3);
        k_smooth<<<g48c, B, 0, stream>>>(oth, cur, D48, 1, 3);
        k_smooth<<<g48c, B, 0, stream>>>(cur, oth, D48, 2, 3);
        float* tmp = cur; cur = oth; oth = tmp;
    }

    // ---- Level 1 (96^3) ----
    k_upsample_vf<<<g96c, B, 0, stream>>>(cur, vfA96);
    float* cur9 = vfA96; float* oth9 = vfB96;
    for (int it = 0; it < 2; ++it) {
        k_warp<<<g96, B, 0, stream>>>(moving, cur9, wrp96, D96);
        k_forces<<<g96, B, 0, stream>>>(wrp96, image, mask, spacing, cur9, D96, D96, 2.0f);
        k_smooth<<<g96c, B, 0, stream>>>(cur9, oth9, D96, 0, 3);
        k_smooth<<<g96c, B, 0, stream>>>(oth9, cur9, D96, 1, 3);
        k_smooth<<<g96c, B, 0, stream>>>(cur9, oth9, D96, 2, 3);
        float* tmp = cur9; cur9 = oth9; oth9 = tmp;
    }
    // cur9 == vfA96 here (final vf), oth9 == vfB96 free

    // ---- CNN ----
    k_warp<<<g96, B, 0, stream>>>(moving, cur9, wrp96, D96);
    k_pack<<<g96, B, 0, stream>>>(cur9, image, mask, wrp96, xin);

    k_conv3<5, 4, float, __hip_bfloat16><<<dim3(1728, 8), 512, 0, stream>>>(xin, w1, nullptr, y1);
    k_stats1<__hip_bfloat16><<<dim3(256, 32), 512, 0, stream>>>(y1, part, N96);
    k_stats_reduce<<<32, 256, 0, stream>>>(part, stats, 256, N96);
    k_norm_mish<__hip_bfloat16><<<dim3(g96, 32), B, 0, stream>>>(y1, stats);

    k_conv3<32, 4, __hip_bfloat16, __hip_bfloat16><<<dim3(1728, 16), 512, 0, stream>>>(y1, w2, nullptr, y2);
    k_stats1<__hip_bfloat16><<<dim3(256, 64), 512, 0, stream>>>(y2, part, N96);
    k_stats_reduce<<<64, 256, 0, stream>>>(part, stats, 256, N96);
    k_norm_mish<__hip_bfloat16><<<dim3(g96, 64), B, 0, stream>>>(y2, stats);

    // conv3 output reuses y1 buffer
    k_conv3<64, 4, __hip_bfloat16, __hip_bfloat16><<<dim3(1728, 8), 512, 0, stream>>>(y2, w3, nullptr, y1);
    k_stats1<__hip_bfloat16><<<dim3(256, 32), 512, 0, stream>>>(y1, part, N96);
    k_stats_reduce<<<32, 256, 0, stream>>>(part, stats, 256, N96);
    k_norm_mish<__hip_bfloat16><<<dim3(g96, 32), B, 0, stream>>>(y1, stats);

    // conv4 (+bias) -> vfC96 (f32)
    k_conv3<32, 3, __hip_bfloat16, float><<<dim3(1728, 1), 512, 0, stream>>>(y1, w4, b4, vfC96);

    // corrected_vf = smooth3d(vf + correction); final x-pass writes straight to d_out
    k_add3<<<g96c, B, 0, stream>>>(vfC96, cur9);
    k_smooth<<<g96c, B, 0, stream>>>(vfC96, oth9, D96, 0, 3);
    k_smooth<<<g96c, B, 0, stream>>>(oth9, vfC96, D96, 1, 3);
    k_smooth<<<g96c, B, 0, stream>>>(vfC96, out + N96, D96, 2, 3);

    // vf output
    k_copy<<<g96c, B, 0, stream>>>(cur9, out + (size_t)4 * N96, 3 * N96);

    // corrected_warped_moving
    k_warp<<<g96, B, 0, stream>>>(moving, out + N96, out, D96);
}

// Round 2
// 1582.477 us; speedup vs baseline: 3.7276x; 3.7276x over previous
//
#include <hip/hip_runtime.h>
#include <hip/hip_bf16.h>
#include <math.h>

#define DEV __device__ __forceinline__

constexpr int D96 = 96;
constexpr int N96 = D96 * D96 * D96;      // 884736
constexpr int D48 = 48;
constexpr int N48 = D48 * D48 * D48;      // 110592

// Gaussian kernel (sigma=1, radius=3), normalized
#define GW0 0.3990502796524549f
#define GW1 0.2420362293761143f
#define GW2 0.05400558262251696f
#define GW3 0.004433048175243745f

typedef __attribute__((ext_vector_type(8))) short s16x8;
typedef __attribute__((ext_vector_type(4))) short s16x4;
typedef __attribute__((ext_vector_type(4))) float f32x4;

DEV int clampi(int v, int lo, int hi) { return v < lo ? lo : (v > hi ? hi : v); }

DEV short f2bf(float f) { __hip_bfloat16 h = __float2bfloat16(f); short s; __builtin_memcpy(&s, &h, 2); return s; }
DEV float bf2f(short s) { __hip_bfloat16 h; __builtin_memcpy(&h, &s, 2); return __bfloat162float(h); }

// ---------------- resize 96 -> 48, trilinear antialias (4-tap 1,3,3,1 /8, edge renorm)
__global__ void k_downsample2x(const float* __restrict__ src, float* __restrict__ dst)
{
    int idx = blockIdx.x * blockDim.x + threadIdx.x;
    if (idx >= N48) return;
    int x = idx % D48, y = (idx / D48) % D48, z = idx / (D48 * D48);

    float wz[4], wy[4], wx[4];
    int jz[4], jy[4], jx[4];
    auto mk = [](int i, float* w, int* j) {
        const float base[4] = {0.125f, 0.375f, 0.375f, 0.125f};
        float s = 0.f;
        #pragma unroll
        for (int t = 0; t < 4; ++t) {
            int jj = 2 * i - 1 + t;
            bool v = (jj >= 0) && (jj < D96);
            j[t] = v ? jj : 0;
            w[t] = v ? base[t] : 0.f;
            s += w[t];
        }
        float inv = 1.f / s;
        #pragma unroll
        for (int t = 0; t < 4; ++t) w[t] *= inv;
    };
    mk(z, wz, jz); mk(y, wy, jy); mk(x, wx, jx);

    float acc = 0.f;
    #pragma unroll
    for (int a = 0; a < 4; ++a) {
        #pragma unroll
        for (int b = 0; b < 4; ++b) {
            float wab = wz[a] * wy[b];
            int rowoff = (jz[a] * D96 + jy[b]) * D96;
            #pragma unroll
            for (int c = 0; c < 4; ++c)
                acc += wab * wx[c] * src[rowoff + jx[c]];
        }
    }
    dst[idx] = acc;
}

// ---------------- vf upsample 48 -> 96 (trilinear, edge renorm) with *2 magnitude scale
__global__ void k_upsample_vf(const float* __restrict__ src, float* __restrict__ dst)
{
    int idx = blockIdx.x * blockDim.x + threadIdx.x;
    if (idx >= 3 * N96) return;
    int c = idx / N96;
    int s = idx - c * N96;
    int x = s % D96, y = (s / D96) % D96, z = s / (D96 * D96);

    auto mk = [](int i, int* j, float* w) {
        int k = i >> 1;
        if ((i & 1) == 0) { j[0] = k - 1; w[0] = 0.25f; j[1] = k; w[1] = 0.75f; }
        else              { j[0] = k;     w[0] = 0.75f; j[1] = k + 1; w[1] = 0.25f; }
        float sum = 0.f;
        #pragma unroll
        for (int t = 0; t < 2; ++t) {
            bool v = (j[t] >= 0) && (j[t] < D48);
            if (!v) { w[t] = 0.f; j[t] = 0; }
            sum += w[t];
        }
        float inv = 1.f / sum;
        w[0] *= inv; w[1] *= inv;
    };
    int jz[2], jy[2], jx[2]; float wz[2], wy[2], wx[2];
    mk(z, jz, wz); mk(y, jy, wy); mk(x, jx, wx);

    const float* p = src + (size_t)c * N48;
    float acc = 0.f;
    #pragma unroll
    for (int a = 0; a < 2; ++a)
        #pragma unroll
        for (int b = 0; b < 2; ++b) {
            float wab = wz[a] * wy[b];
            int rowoff = (jz[a] * D48 + jy[b]) * D48;
            acc += wab * (wx[0] * p[rowoff + jx[0]] + wx[1] * p[rowoff + jx[1]]);
        }
    dst[idx] = 2.f * acc;   // per-axis magnitude scale 96/48
}

// ---------------- trilinear warp, mode='nearest' (clamped indices)
__global__ void k_warp(const float* __restrict__ img, const float* __restrict__ vf,
                       float* __restrict__ out, int D)
{
    int N = D * D * D;
    int idx = blockIdx.x * blockDim.x + threadIdx.x;
    if (idx >= N) return;
    int x = idx % D, y = (idx / D) % D, z = idx / (D * D);
    float cz = z + vf[idx], cy = y + vf[N + idx], cx = x + vf[2 * N + idx];
    float fz = floorf(cz), fy = floorf(cy), fx = floorf(cx);
    float wz = cz - fz, wy = cy - fy, wx = cx - fx;
    int z0 = clampi((int)fz, 0, D - 1), z1 = clampi((int)fz + 1, 0, D - 1);
    int y0 = clampi((int)fy, 0, D - 1), y1 = clampi((int)fy + 1, 0, D - 1);
    int x0 = clampi((int)fx, 0, D - 1), x1 = clampi((int)fx + 1, 0, D - 1);
    float v000 = img[(z0 * D + y0) * D + x0], v001 = img[(z0 * D + y0) * D + x1];
    float v010 = img[(z0 * D + y1) * D + x0], v011 = img[(z0 * D + y1) * D + x1];
    float v100 = img[(z1 * D + y0) * D + x0], v101 = img[(z1 * D + y0) * D + x1];
    float v110 = img[(z1 * D + y1) * D + x0], v111 = img[(z1 * D + y1) * D + x1];
    float c00 = v000 + wx * (v001 - v000);
    float c01 = v010 + wx * (v011 - v010);
    float c10 = v100 + wx * (v101 - v100);
    float c11 = v110 + wx * (v111 - v110);
    float c0 = c00 + wy * (c01 - c00);
    float c1 = c10 + wy * (c11 - c10);
    out[idx] = c0 + wz * (c1 - c0);
}

// ---------------- demon forces + vf update (in place)
__global__ void k_forces(const float* __restrict__ warped, const float* __restrict__ fixed,
                         const float* __restrict__ mask, const float* __restrict__ spacing,
                         float* __restrict__ vf, int D, int maskD, float tau)
{
    int N = D * D * D;
    int idx = blockIdx.x * blockDim.x + threadIdx.x;
    if (idx >= N) return;
    int x = idx % D, y = (idx / D) % D, z = idx / (D * D);
    float w0 = warped[idx];
    float diff = w0 - fixed[idx];
    int sZ = D * D, sY = D;
    float gz = (z == 0) ? warped[idx + sZ] - w0 : (z == D - 1) ? w0 - warped[idx - sZ]
               : 0.5f * (warped[idx + sZ] - warped[idx - sZ]);
    float gy = (y == 0) ? warped[idx + sY] - w0 : (y == D - 1) ? w0 - warped[idx - sY]
               : 0.5f * (warped[idx + sY] - warped[idx - sY]);
    float gx = (x == 0) ? warped[idx + 1] - w0 : (x == D - 1) ? w0 - warped[idx - 1]
               : 0.5f * (warped[idx + 1] - warped[idx - 1]);
    gz /= spacing[0]; gy /= spacing[1]; gx /= spacing[2];
    float denom = gz * gz + gy * gy + gx * gx + diff * diff;
    float m;
    if (D == maskD) m = mask[idx];
    else {
        float r = (float)maskD / (float)D;
        int mz = clampi((int)((z + 0.5f) * r), 0, maskD - 1);
        int my = clampi((int)((y + 0.5f) * r), 0, maskD - 1);
        int mx = clampi((int)((x + 0.5f) * r), 0, maskD - 1);
        m = mask[(mz * maskD + my) * maskD + mx];
    }
    if (denom > 1e-9f) {
        float sc = tau * diff / denom * m;
        vf[idx]         += sc * gz;
        vf[N + idx]     += sc * gy;
        vf[2 * N + idx] += sc * gx;
    }
}

// ---------------- separable 7-tap Gaussian along one axis, zero padding, nch channels
__global__ void k_smooth(const float* __restrict__ src, float* __restrict__ dst,
                         int D, int axis, int nch)
{
    int N = D * D * D;
    int total = nch * N;
    int idx = blockIdx.x * blockDim.x + threadIdx.x;
    if (idx >= total) return;
    int s = idx % N;
    int x = s % D, y = (s / D) % D, z = s / (D * D);
    int a = (axis == 0) ? z : (axis == 1) ? y : x;
    int stride = (axis == 0) ? D * D : (axis == 1) ? D : 1;
    const float w[4] = {GW0, GW1, GW2, GW3};
    float acc = w[0] * src[idx];
    #pragma unroll
    for (int t = 1; t <= 3; ++t) {
        if (a - t >= 0) acc += w[t] * src[idx - t * stride];
        if (a + t < D)  acc += w[t] * src[idx + t * stride];
    }
    dst[idx] = acc;
}

// ---------------- pack CNN input channels-last bf16: [vox][8] = {vf0,vf1,vf2,img*mask,warped,0,0,0}
__global__ void k_pack_cl(const float* __restrict__ vf, const float* __restrict__ image,
                          const float* __restrict__ mask, const float* __restrict__ warped,
                          short* __restrict__ xin8)
{
    int i = blockIdx.x * blockDim.x + threadIdx.x;
    if (i >= N96) return;
    s16x8 v;
    v[0] = f2bf(vf[i]); v[1] = f2bf(vf[N96 + i]); v[2] = f2bf(vf[2 * N96 + i]);
    v[3] = f2bf(image[i] * mask[i]); v[4] = f2bf(warped[i]);
    v[5] = 0; v[6] = 0; v[7] = 0;
    *reinterpret_cast<s16x8*>(&xin8[(size_t)i * 8]) = v;
}

// ---------------- weight reorder: w[cout][cin][27] f32 -> Wr[coutp][K_PAD] bf16, k=off*CINP+ci
template <int CIN, int CINP, int COUT, int COUTP>
__global__ void k_wreorder(const float* __restrict__ w, short* __restrict__ Wr)
{
    constexpr int KSTEPS = (27 * CINP + 31) / 32;
    constexpr int KP = KSTEPS * 32;
    int i = blockIdx.x * 256 + threadIdx.x;
    if (i >= COUTP * KP) return;
    int co = i / KP, k = i % KP;
    int off = k / CINP, ci = k % CINP;
    float v = 0.f;
    if (co < COUT && ci < CIN && off < 27)
        v = w[((size_t)co * CIN + ci) * 27 + off];
    Wr[i] = f2bf(v);
}

// ---------------- implicit-GEMM MFMA 3x3x3 conv, channels-last bf16
// A = weights [cout x K], B = input patches [K x vox], D[cout][vox]
template <int CINP, int COUTP, int YSUB, int CIN, int COUT, bool F32OUT>
__global__ __launch_bounds__(256, 1)
void k_conv_mfma(const short* __restrict__ act, const short* __restrict__ Wr,
                 short* __restrict__ outcl, float* __restrict__ outf,
                 const float* __restrict__ bias)
{
    constexpr int G  = CINP / 8;                 // 16B granules per voxel
    constexpr int SH = (G == 8) ? 0 : ((G == 4) ? 1 : 3);
    constexpr int YH = YSUB + 2;
    constexpr int KSTEPS = (27 * CINP + 31) / 32;
    constexpr int KP = KSTEPS * 32;
    constexpr int TN = YSUB * 6 / 4;             // n-tiles (16 vox) per wave
    constexpr int TM = COUTP / 16;               // m-tiles per wave
    constexpr int TILE_E = 3 * YH * 98 * CINP;   // input tile elements (bf16)
    constexpr bool WFULL = (TILE_E + COUTP * KP) * 2 <= 150000;
    constexpr int WSZ = WFULL ? COUTP * KP : 2 * COUTP * 32;

    __shared__ __align__(16) short smem[TILE_E + WSZ];
    short* tile = smem;
    short* wlds = smem + TILE_E;

    constexpr int YT = 96 / YSUB;
    int b = blockIdx.x;
    int xcd = b & 7;           // XCD z-slab swizzle: each XCD streams 12 z-planes
    int idx = b >> 3;
    int z  = xcd * 12 + idx / YT;
    int y0 = (idx % YT) * YSUB;

    int tid = threadIdx.x;
    int lane = tid & 63, wave = tid >> 6;
    int ln15 = lane & 15, lg = lane >> 4;

    // stage input tile (zero pad at volume edges), swizzled granule slots
    for (int i = tid; i < TILE_E / 8; i += 256) {
        int g  = i % G;
        int xi = (i / G) % 98;
        int rem = i / (G * 98);
        int yi = rem % YH;
        int zi = rem / YH;
        int gz = z + zi - 1, gy = y0 + yi - 1, gx = xi - 1;
        s16x8 v = {0, 0, 0, 0, 0, 0, 0, 0};
        if ((unsigned)gz < 96u && (unsigned)gy < 96u && (unsigned)gx < 96u)
            v = *reinterpret_cast<const s16x8*>(&act[(size_t)(((gz * D96 + gy) * D96) + gx) * CINP + g * 8]);
        int slot = g ^ ((xi >> SH) & (G - 1));
        *reinterpret_cast<s16x8*>(&tile[((zi * YH + yi) * 98 + xi) * CINP + slot * 8]) = v;
    }
    // stage weights
    if (WFULL) {
        for (int i = tid; i < COUTP * KSTEPS * 4; i += 256) {
            int sgl = i % (KSTEPS * 4);
            int co  = i / (KSTEPS * 4);
            s16x8 v = *reinterpret_cast<const s16x8*>(&Wr[(size_t)co * KP + sgl * 8]);
            *reinterpret_cast<s16x8*>(&wlds[(co * (KSTEPS * 4) + (sgl ^ ((co >> 1) & 3))) * 8]) = v;
        }
    } else {
        if (tid < COUTP * 4) {
            int co = tid >> 2, s = tid & 3;
            s16x8 v = *reinterpret_cast<const s16x8*>(&Wr[(size_t)co * KP + s * 8]);
            *reinterpret_cast<s16x8*>(&wlds[(co * 4 + (s ^ ((co >> 1) & 3))) * 8]) = v;
        }
    }
    __syncthreads();

    f32x4 acc[TN][TM];
    #pragma unroll
    for (int i = 0; i < TN; ++i)
        #pragma unroll
        for (int m = 0; m < TM; ++m) acc[i][m] = {0.f, 0.f, 0.f, 0.f};

    for (int ks = 0; ks < KSTEPS; ++ks) {
        if (!WFULL && ks + 1 < KSTEPS) {
            // prefetch next K-slice of weights into the other buffer
            if (tid < COUTP * 4) {
                int co = tid >> 2, s = tid & 3;
                s16x8 v = *reinterpret_cast<const s16x8*>(&Wr[(size_t)co * KP + (ks + 1) * 32 + s * 8]);
                *reinterpret_cast<s16x8*>(&wlds[(((ks + 1) & 1) * COUTP * 32) + (co * 4 + (s ^ ((co >> 1) & 3))) * 8]) = v;
            }
        }
        // A fragments (weights)
        s16x8 a[TM];
        #pragma unroll
        for (int m = 0; m < TM; ++m) {
            int cl = m * 16 + ln15;
            int off_a;
            if (WFULL) off_a = (cl * (KSTEPS * 4) + ((ks * 4 + lg) ^ ((cl >> 1) & 3))) * 8;
            else       off_a = ((ks & 1) * COUTP * 32) + (cl * 4 + (lg ^ ((cl >> 1) & 3))) * 8;
            a[m] = *reinterpret_cast<const s16x8*>(&wlds[off_a]);
        }
        // per-lane spatial offset for this k-chunk
        int kg = ks * 32 + lg * 8;
        int off = kg / CINP; if (off > 26) off = 26;   // padded-k lanes: weights are 0
        int dz = off / 9; int r9 = off - dz * 9; int dy = r9 / 3; int dx = r9 - dy * 3;
        int gB = (kg % CINP) >> 3;
        #pragma unroll
        for (int i = 0; i < TN; ++i) {
            int nt = wave * TN + i;
            int yl = nt / 6, xt = nt - yl * 6;
            int xx = xt * 16 + ln15 + dx;
            int gidx = ((dz * YH + yl + dy) * 98 + xx) * G + (gB ^ ((xx >> SH) & (G - 1)));
            s16x8 bf = *reinterpret_cast<const s16x8*>(&tile[gidx * 8]);
            #pragma unroll
            for (int m = 0; m < TM; ++m)
                acc[i][m] = __builtin_amdgcn_mfma_f32_16x16x32_bf16(a[m], bf, acc[i][m], 0, 0, 0);
        }
        if (!WFULL) __syncthreads();
    }

    // epilogue: D row = cout = lg*4+r (+16m), col = vox = ln15
    #pragma unroll
    for (int i = 0; i < TN; ++i) {
        int nt = wave * TN + i;
        int yl = nt / 6, xt = nt - yl * 6;
        int vox = ((z * D96) + y0 + yl) * D96 + xt * 16 + ln15;
        if constexpr (F32OUT) {
            #pragma unroll
            for (int r = 0; r < 4; ++r) {
                int c = lg * 4 + r;
                if (c < COUT) outf[(size_t)c * N96 + vox] = acc[i][0][r] + bias[c];
            }
        } else {
            #pragma unroll
            for (int m = 0; m < TM; ++m) {
                s16x4 pk;
                #pragma unroll
                for (int r = 0; r < 4; ++r) pk[r] = f2bf(acc[i][m][r]);
                *reinterpret_cast<s16x4*>(&outcl[(size_t)vox * COUTP + m * 16 + lg * 4]) = pk;
            }
        }
    }
}

// ---------------- instance-norm stats, channels-last: per-block partials (deterministic)
template <int C>
__global__ void k_stats_cl(const short* __restrict__ x, float* __restrict__ part)
{
    constexpr int G8 = C / 8;
    int t = threadIdx.x;
    int gt = blockIdx.x * 256 + t;
    float fs[8], fq[8];
    #pragma unroll
    for (int j = 0; j < 8; ++j) { fs[j] = 0.f; fq[j] = 0.f; }
    const int TGn = N96 * G8;
    for (int i = gt; i < TGn; i += 256 * 256) {
        s16x8 v = *reinterpret_cast<const s16x8*>(&x[(size_t)i * 8]);
        #pragma unroll
        for (int j = 0; j < 8; ++j) { float f = bf2f(v[j]); fs[j] += f; fq[j] += f * f; }
    }
    // thread's channel-group cg = t % G8 is constant; reduce lanes sharing cg
    for (int off = G8; off < 64; off <<= 1) {
        #pragma unroll
        for (int j = 0; j < 8; ++j) { fs[j] += __shfl_down(fs[j], off); fq[j] += __shfl_down(fq[j], off); }
    }
    __shared__ float red[4][G8][16];
    int lane = t & 63, wave = t >> 6;
    if (lane < G8) {
        #pragma unroll
        for (int j = 0; j < 8; ++j) { red[wave][lane][j] = fs[j]; red[wave][lane][8 + j] = fq[j]; }
    }
    __syncthreads();
    if (t < G8 * 8) {
        int cg = t >> 3, j = t & 7;
        float s = 0.f, q = 0.f;
        #pragma unroll
        for (int w = 0; w < 4; ++w) { s += red[w][cg][j]; q += red[w][cg][8 + j]; }
        int c = cg * 8 + j;
        part[((size_t)c * 256 + blockIdx.x) * 2]     = s;
        part[((size_t)c * 256 + blockIdx.x) * 2 + 1] = q;
    }
}

// stage 2: reduce partials/channel -> mean + inv_std
__global__ void k_stats_reduce(const float* __restrict__ part, float* __restrict__ stats,
                               int G, int N)
{
    int c = blockIdx.x;
    int t = threadIdx.x;
    float s = 0.f, s2 = 0.f;
    for (int i = t; i < G; i += blockDim.x) {
        s  += part[((size_t)c * G + i) * 2];
        s2 += part[((size_t)c * G + i) * 2 + 1];
    }
    #pragma unroll
    for (int o = 32; o > 0; o >>= 1) { s += __shfl_down(s, o); s2 += __shfl_down(s2, o); }
    __shared__ float a[4], b[4];
    int lane = t & 63, wid = t >> 6;
    if (lane == 0) { a[wid] = s; b[wid] = s2; }
    __syncthreads();
    if (t == 0) {
        float ss = a[0] + a[1] + a[2] + a[3];
        float qq = b[0] + b[1] + b[2] + b[3];
        float mean = ss / (float)N;
        float var = qq / (float)N - mean * mean;
        stats[2 * c] = mean;
        stats[2 * c + 1] = rsqrtf(var + 1e-5f);
    }
}

// ---------------- (x - mean) * inv, then mish, channels-last in place
template <int C>
__global__ void k_norm_mish_cl(short* __restrict__ x, const float* __restrict__ stats)
{
    constexpr int G8 = C / 8;
    int gt = blockIdx.x * 256 + threadIdx.x;
    int cg = threadIdx.x % G8;
    float mean[8], inv[8];
    #pragma unroll
    for (int j = 0; j < 8; ++j) { mean[j] = stats[2 * (cg * 8 + j)]; inv[j] = stats[2 * (cg * 8 + j) + 1]; }
    const int TGn = N96 * G8;
    int stride = gridDim.x * 256;
    for (int i = gt; i < TGn; i += stride) {
        s16x8 v = *reinterpret_cast<const s16x8*>(&x[(size_t)i * 8]);
        #pragma unroll
        for (int j = 0; j < 8; ++j) {
            float f = (bf2f(v[j]) - mean[j]) * inv[j];
            float sp = (f > 20.f) ? f : log1pf(expf(f));
            v[j] = f2bf(f * tanhf(sp));
        }
        *reinterpret_cast<s16x8*>(&x[(size_t)i * 8]) = v;
    }
}

__global__ void k_add3(float* __restrict__ dst, const float* __restrict__ src)
{
    int idx = blockIdx.x * blockDim.x + threadIdx.x;
    if (idx >= 3 * N96) return;
    dst[idx] += src[idx];
}

__global__ void k_copy(const float* __restrict__ src, float* __restrict__ dst, int n)
{
    int idx = blockIdx.x * blockDim.x + threadIdx.x;
    if (idx >= n) return;
    dst[idx] = src[idx];
}

extern "C" void kernel_launch(void* const* d_in, const int* in_sizes, int n_in,
                              void* d_out, int out_size, void* d_ws, size_t ws_size,
                              hipStream_t stream)
{
    const float* image   = (const float*)d_in[0];
    const float* mask    = (const float*)d_in[1];
    const float* moving  = (const float*)d_in[2];
    const float* spacing = (const float*)d_in[3];
    const float* w1 = (const float*)d_in[4];
    const float* w2 = (const float*)d_in[5];
    const float* w3 = (const float*)d_in[6];
    const float* w4 = (const float*)d_in[7];
    const float* b4 = (const float*)d_in[8];
    float* out = (float*)d_out;

    char* ws = (char*)d_ws;
    size_t off = 0;
    auto alloc = [&](size_t bytes) -> char* {
        char* p = ws + off;
        off += (bytes + 255) & ~(size_t)255;
        return p;
    };
    float* f48   = (float*)alloc((size_t)N48 * 4);
    float* mv48  = (float*)alloc((size_t)N48 * 4);
    float* vfA48 = (float*)alloc((size_t)3 * N48 * 4);
    float* vfB48 = (float*)alloc((size_t)3 * N48 * 4);
    float* wrp48 = (float*)alloc((size_t)N48 * 4);
    float* vfA96 = (float*)alloc((size_t)3 * N96 * 4);
    float* vfB96 = (float*)alloc((size_t)3 * N96 * 4);
    float* vfC96 = (float*)alloc((size_t)3 * N96 * 4);
    float* wrp96 = (float*)alloc((size_t)N96 * 4);
    short* xin8  = (short*)alloc((size_t)8 * N96 * 2);
    short* y1    = (short*)alloc((size_t)32 * N96 * 2);
    short* y2    = (short*)alloc((size_t)64 * N96 * 2);
    short* wr1   = (short*)alloc((size_t)32 * 224 * 2);
    short* wr2   = (short*)alloc((size_t)64 * 864 * 2);
    short* wr3   = (short*)alloc((size_t)32 * 1728 * 2);
    short* wr4   = (short*)alloc((size_t)16 * 864 * 2);
    float* part  = (float*)alloc((size_t)64 * 256 * 2 * 4);
    float* stats = (float*)alloc((size_t)64 * 2 * 4);

    const int B = 256;
    const int g48  = (N48 + B - 1) / B;
    const int g48c = (3 * N48 + B - 1) / B;
    const int g96  = (N96 + B - 1) / B;
    const int g96c = (3 * N96 + B - 1) / B;

    // ---- weight reorders (independent of registration) ----
    k_wreorder<5, 8, 32, 32><<<(32 * 224 + 255) / 256, B, 0, stream>>>(w1, wr1);
    k_wreorder<32, 32, 64, 64><<<(64 * 864 + 255) / 256, B, 0, stream>>>(w2, wr2);
    k_wreorder<64, 64, 32, 32><<<(32 * 1728 + 255) / 256, B, 0, stream>>>(w3, wr3);
    k_wreorder<32, 32, 3, 16><<<(16 * 864 + 255) / 256, B, 0, stream>>>(w4, wr4);

    // ---- Level 0 (48^3) ----
    k_downsample2x<<<g48, B, 0, stream>>>(image, f48);
    k_downsample2x<<<g48, B, 0, stream>>>(moving, mv48);
    hipMemsetAsync(vfA48, 0, (size_t)3 * N48 * 4, stream);
    float* cur = vfA48; float* oth = vfB48;
    for (int it = 0; it < 2; ++it) {
        k_warp<<<g48, B, 0, stream>>>(mv48, cur, wrp48, D48);
        k_forces<<<g48, B, 0, stream>>>(wrp48, f48, mask, spacing, cur, D48, D96, 2.0f);
        k_smooth<<<g48c, B, 0, stream>>>(cur, oth, D48, 0, 3);
        k_smooth<<<g48c, B, 0, stream>>>(oth, cur, D48, 1, 3);
        k_smooth<<<g48c, B, 0, stream>>>(cur, oth, D48, 2, 3);
        float* tmp = cur; cur = oth; oth = tmp;
    }

    // ---- Level 1 (96^3) ----
    k_upsample_vf<<<g96c, B, 0, stream>>>(cur, vfA96);
    float* cur9 = vfA96; float* oth9 = vfB96;
    for (int it = 0; it < 2; ++it) {
        k_warp<<<g96, B, 0, stream>>>(moving, cur9, wrp96, D96);
        k_forces<<<g96, B, 0, stream>>>(wrp96, image, mask, spacing, cur9, D96, D96, 2.0f);
        k_smooth<<<g96c, B, 0, stream>>>(cur9, oth9, D96, 0, 3);
        k_smooth<<<g96c, B, 0, stream>>>(oth9, cur9, D96, 1, 3);
        k_smooth<<<g96c, B, 0, stream>>>(cur9, oth9, D96, 2, 3);
        float* tmp = cur9; cur9 = oth9; oth9 = tmp;
    }
    // cur9 == vfA96 here (final vf)

    // ---- CNN ----
    k_warp<<<g96, B, 0, stream>>>(moving, cur9, wrp96, D96);
    k_pack_cl<<<g96, B, 0, stream>>>(cur9, image, mask, wrp96, xin8);

    // conv1: 8(5)->32
    k_conv_mfma<8, 32, 4, 5, 32, false><<<2304, 256, 0, stream>>>(xin8, wr1, y1, nullptr, nullptr);
    k_stats_cl<32><<<256, 256, 0, stream>>>(y1, part);
    k_stats_reduce<<<32, 256, 0, stream>>>(part, stats, 256, N96);
    k_norm_mish_cl<32><<<2048, 256, 0, stream>>>(y1, stats);

    // conv2: 32->64
    k_conv_mfma<32, 64, 4, 32, 64, false><<<2304, 256, 0, stream>>>(y1, wr2, y2, nullptr, nullptr);
    k_stats_cl<64><<<256, 256, 0, stream>>>(y2, part);
    k_stats_reduce<<<64, 256, 0, stream>>>(part, stats, 256, N96);
    k_norm_mish_cl<64><<<2048, 256, 0, stream>>>(y2, stats);

    // conv3: 64->32 (output reuses y1)
    k_conv_mfma<64, 32, 2, 64, 32, false><<<4608, 256, 0, stream>>>(y2, wr3, y1, nullptr, nullptr);
    k_stats_cl<32><<<256, 256, 0, stream>>>(y1, part);
    k_stats_reduce<<<32, 256, 0, stream>>>(part, stats, 256, N96);
    k_norm_mish_cl<32><<<2048, 256, 0, stream>>>(y1, stats);

    // conv4: 32->3 (+bias), f32 channel-first output
    k_conv_mfma<32, 16, 4, 32, 3, true><<<2304, 256, 0, stream>>>(y1, wr4, nullptr, vfC96, b4);

    // corrected_vf = smooth3d(vf + correction); final x-pass writes straight to d_out
    k_add3<<<g96c, B, 0, stream>>>(vfC96, cur9);
    k_smooth<<<g96c, B, 0, stream>>>(vfC96, oth9, D96, 0, 3);
    k_smooth<<<g96c, B, 0, stream>>>(oth9, vfC96, D96, 1, 3);
    k_smooth<<<g96c, B, 0, stream>>>(vfC96, out + N96, D96, 2, 3);

    // vf output
    k_copy<<<g96c, B, 0, stream>>>(cur9, out + (size_t)4 * N96, 3 * N96);

    // corrected_warped_moving
    k_warp<<<g96, B, 0, stream>>>(moving, out + N96, out, D96);
}

// Round 3
// 900.821 us; speedup vs baseline: 6.5482x; 1.7567x over previous
//
#include <hip/hip_runtime.h>
#include <hip/hip_bf16.h>
#include <math.h>

#define DEV __device__ __forceinline__

constexpr int D96 = 96;
constexpr int N96 = D96 * D96 * D96;      // 884736
constexpr int D48 = 48;
constexpr int N48 = D48 * D48 * D48;      // 110592

// Gaussian kernel (sigma=1, radius=3), normalized
#define GW0 0.3990502796524549f
#define GW1 0.2420362293761143f
#define GW2 0.05400558262251696f
#define GW3 0.004433048175243745f

typedef __attribute__((ext_vector_type(8))) short s16x8;
typedef __attribute__((ext_vector_type(4))) short s16x4;
typedef __attribute__((ext_vector_type(4))) float f32x4;
typedef __attribute__((ext_vector_type(16))) float f32x16;

DEV int clampi(int v, int lo, int hi) { return v < lo ? lo : (v > hi ? hi : v); }

DEV short f2bf(float f) { __hip_bfloat16 h = __float2bfloat16(f); short s; __builtin_memcpy(&s, &h, 2); return s; }
DEV float bf2f(short s) { __hip_bfloat16 h; __builtin_memcpy(&h, &s, 2); return __bfloat162float(h); }

// ---------------- resize 96 -> 48, trilinear antialias (4-tap 1,3,3,1 /8, edge renorm)
__global__ void k_downsample2x(const float* __restrict__ src, float* __restrict__ dst)
{
    int idx = blockIdx.x * blockDim.x + threadIdx.x;
    if (idx >= N48) return;
    int x = idx % D48, y = (idx / D48) % D48, z = idx / (D48 * D48);

    float wz[4], wy[4], wx[4];
    int jz[4], jy[4], jx[4];
    auto mk = [](int i, float* w, int* j) {
        const float base[4] = {0.125f, 0.375f, 0.375f, 0.125f};
        float s = 0.f;
        #pragma unroll
        for (int t = 0; t < 4; ++t) {
            int jj = 2 * i - 1 + t;
            bool v = (jj >= 0) && (jj < D96);
            j[t] = v ? jj : 0;
            w[t] = v ? base[t] : 0.f;
            s += w[t];
        }
        float inv = 1.f / s;
        #pragma unroll
        for (int t = 0; t < 4; ++t) w[t] *= inv;
    };
    mk(z, wz, jz); mk(y, wy, jy); mk(x, wx, jx);

    float acc = 0.f;
    #pragma unroll
    for (int a = 0; a < 4; ++a) {
        #pragma unroll
        for (int b = 0; b < 4; ++b) {
            float wab = wz[a] * wy[b];
            int rowoff = (jz[a] * D96 + jy[b]) * D96;
            #pragma unroll
            for (int c = 0; c < 4; ++c)
                acc += wab * wx[c] * src[rowoff + jx[c]];
        }
    }
    dst[idx] = acc;
}

// ---------------- vf upsample 48 -> 96 (trilinear, edge renorm) with *2 magnitude scale
__global__ void k_upsample_vf(const float* __restrict__ src, float* __restrict__ dst)
{
    int idx = blockIdx.x * blockDim.x + threadIdx.x;
    if (idx >= 3 * N96) return;
    int c = idx / N96;
    int s = idx - c * N96;
    int x = s % D96, y = (s / D96) % D96, z = s / (D96 * D96);

    auto mk = [](int i, int* j, float* w) {
        int k = i >> 1;
        if ((i & 1) == 0) { j[0] = k - 1; w[0] = 0.25f; j[1] = k; w[1] = 0.75f; }
        else              { j[0] = k;     w[0] = 0.75f; j[1] = k + 1; w[1] = 0.25f; }
        float sum = 0.f;
        #pragma unroll
        for (int t = 0; t < 2; ++t) {
            bool v = (j[t] >= 0) && (j[t] < D48);
            if (!v) { w[t] = 0.f; j[t] = 0; }
            sum += w[t];
        }
        float inv = 1.f / sum;
        w[0] *= inv; w[1] *= inv;
    };
    int jz[2], jy[2], jx[2]; float wz[2], wy[2], wx[2];
    mk(z, jz, wz); mk(y, jy, wy); mk(x, jx, wx);

    const float* p = src + (size_t)c * N48;
    float acc = 0.f;
    #pragma unroll
    for (int a = 0; a < 2; ++a)
        #pragma unroll
        for (int b = 0; b < 2; ++b) {
            float wab = wz[a] * wy[b];
            int rowoff = (jz[a] * D48 + jy[b]) * D48;
            acc += wab * (wx[0] * p[rowoff + jx[0]] + wx[1] * p[rowoff + jx[1]]);
        }
    dst[idx] = 2.f * acc;   // per-axis magnitude scale 96/48
}

// ---------------- trilinear warp, mode='nearest' (clamped indices)
__global__ void k_warp(const float* __restrict__ img, const float* __restrict__ vf,
                       float* __restrict__ out, int D)
{
    int N = D * D * D;
    int idx = blockIdx.x * blockDim.x + threadIdx.x;
    if (idx >= N) return;
    int x = idx % D, y = (idx / D) % D, z = idx / (D * D);
    float cz = z + vf[idx], cy = y + vf[N + idx], cx = x + vf[2 * N + idx];
    float fz = floorf(cz), fy = floorf(cy), fx = floorf(cx);
    float wz = cz - fz, wy = cy - fy, wx = cx - fx;
    int z0 = clampi((int)fz, 0, D - 1), z1 = clampi((int)fz + 1, 0, D - 1);
    int y0 = clampi((int)fy, 0, D - 1), y1 = clampi((int)fy + 1, 0, D - 1);
    int x0 = clampi((int)fx, 0, D - 1), x1 = clampi((int)fx + 1, 0, D - 1);
    float v000 = img[(z0 * D + y0) * D + x0], v001 = img[(z0 * D + y0) * D + x1];
    float v010 = img[(z0 * D + y1) * D + x0], v011 = img[(z0 * D + y1) * D + x1];
    float v100 = img[(z1 * D + y0) * D + x0], v101 = img[(z1 * D + y0) * D + x1];
    float v110 = img[(z1 * D + y1) * D + x0], v111 = img[(z1 * D + y1) * D + x1];
    float c00 = v000 + wx * (v001 - v000);
    float c01 = v010 + wx * (v011 - v010);
    float c10 = v100 + wx * (v101 - v100);
    float c11 = v110 + wx * (v111 - v110);
    float c0 = c00 + wy * (c01 - c00);
    float c1 = c10 + wy * (c11 - c10);
    out[idx] = c0 + wz * (c1 - c0);
}

// ---------------- demon forces + vf update (in place)
__global__ void k_forces(const float* __restrict__ warped, const float* __restrict__ fixed,
                         const float* __restrict__ mask, const float* __restrict__ spacing,
                         float* __restrict__ vf, int D, int maskD, float tau)
{
    int N = D * D * D;
    int idx = blockIdx.x * blockDim.x + threadIdx.x;
    if (idx >= N) return;
    int x = idx % D, y = (idx / D) % D, z = idx / (D * D);
    float w0 = warped[idx];
    float diff = w0 - fixed[idx];
    int sZ = D * D, sY = D;
    float gz = (z == 0) ? warped[idx + sZ] - w0 : (z == D - 1) ? w0 - warped[idx - sZ]
               : 0.5f * (warped[idx + sZ] - warped[idx - sZ]);
    float gy = (y == 0) ? warped[idx + sY] - w0 : (y == D - 1) ? w0 - warped[idx - sY]
               : 0.5f * (warped[idx + sY] - warped[idx - sY]);
    float gx = (x == 0) ? warped[idx + 1] - w0 : (x == D - 1) ? w0 - warped[idx - 1]
               : 0.5f * (warped[idx + 1] - warped[idx - 1]);
    gz /= spacing[0]; gy /= spacing[1]; gx /= spacing[2];
    float denom = gz * gz + gy * gy + gx * gx + diff * diff;
    float m;
    if (D == maskD) m = mask[idx];
    else {
        float r = (float)maskD / (float)D;
        int mz = clampi((int)((z + 0.5f) * r), 0, maskD - 1);
        int my = clampi((int)((y + 0.5f) * r), 0, maskD - 1);
        int mx = clampi((int)((x + 0.5f) * r), 0, maskD - 1);
        m = mask[(mz * maskD + my) * maskD + mx];
    }
    if (denom > 1e-9f) {
        float sc = tau * diff / denom * m;
        vf[idx]         += sc * gz;
        vf[N + idx]     += sc * gy;
        vf[2 * N + idx] += sc * gx;
    }
}

// ---------------- fused 3-axis separable 7-tap Gaussian, zero pad; 16^3 tile, 22^3 halo
__global__ __launch_bounds__(256, 2)
void k_smooth3(const float* __restrict__ src, float* __restrict__ dst, int D)
{
    __shared__ float B1[10648];       // 22^3 staged input
    __shared__ float B2[7744];        // 16*22*22 after z-pass
    float* B3 = B1;                   // 16*16*22 after y-pass (overlays dead B1)
    int nt = D >> 4;
    int b = blockIdx.x;
    int tx = b % nt, ty = (b / nt) % nt, tz = b / (nt * nt);
    int c = blockIdx.y;
    int N = D * D * D;
    const float* s = src + (size_t)c * N;
    float* d = dst + (size_t)c * N;
    int x0 = tx * 16, y0 = ty * 16, z0 = tz * 16;
    int tid = threadIdx.x;

    for (int l = tid; l < 10648; l += 256) {
        int xx = l % 22, yy = (l / 22) % 22, zz = l / 484;
        int gz = z0 + zz - 3, gy = y0 + yy - 3, gx = x0 + xx - 3;
        float v = 0.f;
        if ((unsigned)gz < (unsigned)D && (unsigned)gy < (unsigned)D && (unsigned)gx < (unsigned)D)
            v = s[((size_t)gz * D + gy) * D + gx];
        B1[l] = v;
    }
    __syncthreads();
    for (int l = tid; l < 16 * 484; l += 256) {
        int xx = l % 22, yy = (l / 22) % 22, zo = l / 484;
        int base = (zo + 3) * 484 + yy * 22 + xx;
        B2[l] = GW0 * B1[base]
              + GW1 * (B1[base - 484] + B1[base + 484])
              + GW2 * (B1[base - 968] + B1[base + 968])
              + GW3 * (B1[base - 1452] + B1[base + 1452]);
    }
    __syncthreads();
    for (int l = tid; l < 16 * 16 * 22; l += 256) {
        int xx = l % 22, yo = (l / 22) % 16, zo = l / 352;
        int base = zo * 484 + (yo + 3) * 22 + xx;
        B3[l] = GW0 * B2[base]
              + GW1 * (B2[base - 22] + B2[base + 22])
              + GW2 * (B2[base - 44] + B2[base + 44])
              + GW3 * (B2[base - 66] + B2[base + 66]);
    }
    __syncthreads();
    for (int l = tid; l < 4096; l += 256) {
        int xo = l % 16, yo = (l / 16) % 16, zo = l / 256;
        int base = zo * 352 + yo * 22 + xo + 3;
        float a = GW0 * B3[base]
                + GW1 * (B3[base - 1] + B3[base + 1])
                + GW2 * (B3[base - 2] + B3[base + 2])
                + GW3 * (B3[base - 3] + B3[base + 3]);
        d[((size_t)(z0 + zo) * D + (y0 + yo)) * D + (x0 + xo)] = a;
    }
}

// ---------------- pack CNN input channels-last bf16: [vox][8] = {vf0,vf1,vf2,img*mask,warped,0,0,0}
__global__ void k_pack_cl(const float* __restrict__ vf, const float* __restrict__ image,
                          const float* __restrict__ mask, const float* __restrict__ warped,
                          short* __restrict__ xin8)
{
    int i = blockIdx.x * blockDim.x + threadIdx.x;
    if (i >= N96) return;
    s16x8 v;
    v[0] = f2bf(vf[i]); v[1] = f2bf(vf[N96 + i]); v[2] = f2bf(vf[2 * N96 + i]);
    v[3] = f2bf(image[i] * mask[i]); v[4] = f2bf(warped[i]);
    v[5] = 0; v[6] = 0; v[7] = 0;
    *reinterpret_cast<s16x8*>(&xin8[(size_t)i * 8]) = v;
}

// ---------------- all weight reorders in one launch.
// Layout: Wr[kg][COUTP][8] bf16, k = kg*8+j, (off,ci) = (k/CINP, k%CINP), off = dz*9+dy*3+dx
__global__ void k_wreorder_all(const float* __restrict__ w1, const float* __restrict__ w2,
                               const float* __restrict__ w3, const float* __restrict__ w4,
                               short* __restrict__ r1, short* __restrict__ r2,
                               short* __restrict__ r3, short* __restrict__ r4)
{
    int i = blockIdx.x * 256 + threadIdx.x;
    const int S1 = 7168, S2 = 55296, S3 = 55296, S4 = 27648;
    const float* w; short* r; int CIN, CINP, COUT, COUTP;
    int idx = i;
    if (idx < S1)              { w = w1; r = r1; CIN = 5;  CINP = 8;  COUT = 32; COUTP = 32; }
    else if ((idx -= S1) < S2) { w = w2; r = r2; CIN = 32; CINP = 32; COUT = 64; COUTP = 64; }
    else if ((idx -= S2) < S3) { w = w3; r = r3; CIN = 64; CINP = 64; COUT = 32; COUTP = 32; }
    else if ((idx -= S3) < S4) { w = w4; r = r4; CIN = 32; CINP = 32; COUT = 3;  COUTP = 32; }
    else return;
    int j = idx & 7;
    int co = (idx >> 3) % COUTP;
    int kg = idx / (8 * COUTP);
    int k = kg * 8 + j;
    int off = k / CINP, ci = k % CINP;
    float v = 0.f;
    if (co < COUT && off < 27 && ci < CIN)
        v = w[((size_t)co * CIN + ci) * 27 + off];
    r[idx] = f2bf(v);
}

// fast mish: x * tanh(softplus(x)) == x - 2x / ((1+e^x)^2 + 1)
DEV float mishf(float f)
{
    float e = __expf(f);
    float t = 1.f + e;
    float u = t * t + 1.f;
    return f - 2.f * f * __builtin_amdgcn_rcpf(u);
}

// ---------------- implicit-GEMM MFMA 3x3x3 conv v2: 32x32x16, rolling z-plane,
// weights from global (L2) w/ reg prefetch, fused input-norm+mish, fused output stats.
// A = weights [cout x K], B = input patches [K x vox], D[cout][vox].
template <int CINP, int COUTP, int CIN, int COUT, bool NORM_IN, bool STATS, bool F32OUT>
__global__ __launch_bounds__(256, 2)
void k_conv_v2(const short* __restrict__ act, const short* __restrict__ Wr,
               short* __restrict__ outcl, float* __restrict__ outf,
               const float* __restrict__ bias, const float* __restrict__ statsIn,
               float* __restrict__ part)
{
    constexpr int G = CINP / 8;               // 16B granules per voxel
    constexpr bool FULLZ = (CINP == 8);       // conv1: stage all 3 planes, pad K
    constexpr int SH = (G == 8) ? 0 : 1;      // swizzle shift (G==4 -> 1; G==8 -> 0; G==1 unused)
    constexpr int YSUB = 4, YH = 6, TN = 3;
    constexpr int TM = COUTP / 32;
    constexpr int KS = FULLZ ? (27 * CINP + 15) / 16 : (9 * CINP) / 16;
    constexpr int TILE_G = FULLZ ? 3 * YH * 98 : YH * 98 * G;   // granules
    __shared__ __align__(16) short tile[TILE_G * 8];
    float* red = (float*)tile;                // epilogue overlay (after final barrier)

    int b = blockIdx.x;
    int xcd = b & 7, bidx = b >> 3;           // XCD z-slab swizzle
    int zblk = xcd * 12 + bidx / 24;
    int y0 = (bidx % 24) * YSUB;

    int tid = threadIdx.x;
    int lane = tid & 63, wave = tid >> 6;
    int ln31 = lane & 31, hi = lane >> 5;

    float nmean[8], ninv[8];
    if constexpr (NORM_IN) {
        int gfix = tid % G;                   // 256 % G == 0 -> fixed per thread
        #pragma unroll
        for (int j = 0; j < 8; ++j) {
            nmean[j] = statsIn[2 * (gfix * 8 + j)];
            ninv[j]  = statsIn[2 * (gfix * 8 + j) + 1];
        }
    }

    int yl_[TN], xb_[TN];
    #pragma unroll
    for (int i = 0; i < TN; ++i) {
        int nt = wave * TN + i;
        yl_[i] = nt / 3;
        xb_[i] = (nt % 3) * 32 + ln31;
    }

    f32x16 acc[TN][TM];
    #pragma unroll
    for (int i = 0; i < TN; ++i)
        #pragma unroll
        for (int m = 0; m < TM; ++m)
            #pragma unroll
            for (int e = 0; e < 16; ++e) acc[i][m][e] = 0.f;

    auto loadA = [&](int kg0, int ks, s16x8* A) {
        #pragma unroll
        for (int m = 0; m < TM; ++m)
            A[m] = *reinterpret_cast<const s16x8*>(
                &Wr[((size_t)(kg0 + ks * 2 + hi) * COUTP + m * 32 + ln31) * 8]);
    };

    if constexpr (FULLZ) {
        for (int i = tid; i < TILE_G; i += 256) {
            int xi = i % 98, yi = (i / 98) % YH, zi = i / (98 * YH);
            int gz = zblk + zi - 1, gy = y0 + yi - 1, gx = xi - 1;
            s16x8 v = {0, 0, 0, 0, 0, 0, 0, 0};
            if ((unsigned)gz < 96u && (unsigned)gy < 96u && (unsigned)gx < 96u)
                v = *reinterpret_cast<const s16x8*>(&act[(size_t)((gz * 96 + gy) * 96 + gx) * 8]);
            *reinterpret_cast<s16x8*>(&tile[i * 8]) = v;
        }
        __syncthreads();
        s16x8 a_cur[TM], a_nxt[TM];
        loadA(0, 0, a_cur);
        for (int ks = 0; ks < KS; ++ks) {
            if (ks + 1 < KS) loadA(0, ks + 1, a_nxt);
            int off = (ks * 16 + hi * 8) >> 3;          // CINP == 8
            if (off > 26) off = 26;                     // padded k: weights are 0
            int dz = off / 9, r9 = off - dz * 9, dy = r9 / 3, dx = r9 - dy * 3;
            #pragma unroll
            for (int i = 0; i < TN; ++i) {
                int gi = (dz * YH + yl_[i] + dy) * 98 + xb_[i] + dx;
                s16x8 bf = *reinterpret_cast<const s16x8*>(&tile[gi * 8]);
                #pragma unroll
                for (int m = 0; m < TM; ++m)
                    acc[i][m] = __builtin_amdgcn_mfma_f32_32x32x16_bf16(a_cur[m], bf, acc[i][m], 0, 0, 0);
            }
            #pragma unroll
            for (int m = 0; m < TM; ++m) a_cur[m] = a_nxt[m];
        }
    } else {
        for (int p = 0; p < 3; ++p) {
            for (int i = tid; i < TILE_G; i += 256) {
                int g = i % G, xi = (i / G) % 98, yi = i / (G * 98);
                int gz = zblk + p - 1, gy = y0 + yi - 1, gx = xi - 1;
                s16x8 v = {0, 0, 0, 0, 0, 0, 0, 0};
                if ((unsigned)gz < 96u && (unsigned)gy < 96u && (unsigned)gx < 96u) {
                    v = *reinterpret_cast<const s16x8*>(
                        &act[(size_t)((gz * 96 + gy) * 96 + gx) * CINP + g * 8]);
                    if constexpr (NORM_IN) {
                        #pragma unroll
                        for (int j = 0; j < 8; ++j)
                            v[j] = f2bf(mishf((bf2f(v[j]) - nmean[j]) * ninv[j]));
                    }
                }
                int slot = g ^ ((xi >> SH) & (G - 1));
                *reinterpret_cast<s16x8*>(&tile[((yi * 98 + xi) * G + slot) * 8]) = v;
            }
            __syncthreads();
            int kg0 = p * (9 * CINP / 8);
            s16x8 a_cur[TM], a_nxt[TM];
            loadA(kg0, 0, a_cur);
            for (int ks = 0; ks < KS; ++ks) {
                if (ks + 1 < KS) loadA(kg0, ks + 1, a_nxt);
                int offl = (ks * 16) / CINP;
                int dy = offl / 3, dx = offl - dy * 3;
                int gsel = (((ks * 16) % CINP) >> 3) + hi;
                #pragma unroll
                for (int i = 0; i < TN; ++i) {
                    int xi = xb_[i] + dx;
                    int gi = (yl_[i] + dy) * (98 * G) + xi * G + (gsel ^ ((xi >> SH) & (G - 1)));
                    s16x8 bf = *reinterpret_cast<const s16x8*>(&tile[gi * 8]);
                    #pragma unroll
                    for (int m = 0; m < TM; ++m)
                        acc[i][m] = __builtin_amdgcn_mfma_f32_32x32x16_bf16(a_cur[m], bf, acc[i][m], 0, 0, 0);
                }
                #pragma unroll
                for (int m = 0; m < TM; ++m) a_cur[m] = a_nxt[m];
            }
            __syncthreads();
        }
    }

    // epilogue: D col = vox = ln31, row(c) = (reg&3) + 8*(reg>>2) + 4*hi (+32m)
    float st_s[TM * 16], st_q[TM * 16];
    if constexpr (STATS) {
        #pragma unroll
        for (int j = 0; j < TM * 16; ++j) { st_s[j] = 0.f; st_q[j] = 0.f; }
    }

    #pragma unroll
    for (int i = 0; i < TN; ++i) {
        int vox = ((zblk * 96) + y0 + yl_[i]) * 96 + xb_[i];
        if constexpr (F32OUT) {
            if (hi == 0) {
                #pragma unroll
                for (int r = 0; r < 3; ++r)
                    outf[(size_t)r * N96 + vox] = acc[i][0][r] + bias[r];
            }
        } else {
            #pragma unroll
            for (int m = 0; m < TM; ++m) {
                #pragma unroll
                for (int q = 0; q < 4; ++q) {
                    s16x4 pk;
                    #pragma unroll
                    for (int r = 0; r < 4; ++r) {
                        float v = acc[i][m][q * 4 + r];
                        if constexpr (STATS) {
                            st_s[m * 16 + q * 4 + r] += v;
                            st_q[m * 16 + q * 4 + r] += v * v;
                        }
                        pk[r] = f2bf(v);
                    }
                    *reinterpret_cast<s16x4*>(&outcl[(size_t)vox * COUTP + m * 32 + q * 8 + hi * 4]) = pk;
                }
            }
        }
    }

    if constexpr (STATS) {
        #pragma unroll
        for (int j = 0; j < TM * 16; ++j) {
            #pragma unroll
            for (int o = 1; o <= 16; o <<= 1) {
                st_s[j] += __shfl_xor(st_s[j], o);
                st_q[j] += __shfl_xor(st_q[j], o);
            }
        }
        __syncthreads();                        // tile reads done -> red overlay safe
        if (ln31 == 0) {
            int base = (wave * 2 + hi) * (TM * 16);
            #pragma unroll
            for (int j = 0; j < TM * 16; ++j) {
                red[(base + j) * 2]     = st_s[j];
                red[(base + j) * 2 + 1] = st_q[j];
            }
        }
        __syncthreads();
        if (tid < COUTP * 2) {
            int c = tid >> 1, sel = tid & 1;
            int m = c >> 5, q = (c >> 3) & 3, hic = (c >> 2) & 1, r = c & 3;
            int j = m * 16 + q * 4 + r;
            float v = 0.f;
            #pragma unroll
            for (int w = 0; w < 4; ++w)
                v += red[((w * 2 + hic) * (TM * 16) + j) * 2 + sel];
            part[((size_t)c * gridDim.x + blockIdx.x) * 2 + sel] = v;
        }
    }
}

// stage 2: reduce per-block partials/channel -> mean + inv_std
__global__ void k_stats_reduce(const float* __restrict__ part, float* __restrict__ stats,
                               int G, int N)
{
    int c = blockIdx.x;
    int t = threadIdx.x;
    float s = 0.f, s2 = 0.f;
    for (int i = t; i < G; i += blockDim.x) {
        s  += part[((size_t)c * G + i) * 2];
        s2 += part[((size_t)c * G + i) * 2 + 1];
    }
    #pragma unroll
    for (int o = 32; o > 0; o >>= 1) { s += __shfl_down(s, o); s2 += __shfl_down(s2, o); }
    __shared__ float a[4], b[4];
    int lane = t & 63, wid = t >> 6;
    if (lane == 0) { a[wid] = s; b[wid] = s2; }
    __syncthreads();
    if (t == 0) {
        float ss = a[0] + a[1] + a[2] + a[3];
        float qq = b[0] + b[1] + b[2] + b[3];
        float mean = ss / (float)N;
        float var = qq / (float)N - mean * mean;
        stats[2 * c] = mean;
        stats[2 * c + 1] = rsqrtf(var + 1e-5f);
    }
}

// dst += vf; also copy vf to outvf (saves a pass)
__global__ void k_add3copy(float* __restrict__ dst, const float* __restrict__ vf,
                           float* __restrict__ outvf)
{
    int idx = blockIdx.x * blockDim.x + threadIdx.x;
    if (idx >= 3 * N96) return;
    float v = vf[idx];
    dst[idx] += v;
    outvf[idx] = v;
}

extern "C" void kernel_launch(void* const* d_in, const int* in_sizes, int n_in,
                              void* d_out, int out_size, void* d_ws, size_t ws_size,
                              hipStream_t stream)
{
    const float* image   = (const float*)d_in[0];
    const float* mask    = (const float*)d_in[1];
    const float* moving  = (const float*)d_in[2];
    const float* spacing = (const float*)d_in[3];
    const float* w1 = (const float*)d_in[4];
    const float* w2 = (const float*)d_in[5];
    const float* w3 = (const float*)d_in[6];
    const float* w4 = (const float*)d_in[7];
    const float* b4 = (const float*)d_in[8];
    float* out = (float*)d_out;

    char* ws = (char*)d_ws;
    size_t off = 0;
    auto alloc = [&](size_t bytes) -> char* {
        char* p = ws + off;
        off += (bytes + 255) & ~(size_t)255;
        return p;
    };
    float* f48   = (float*)alloc((size_t)N48 * 4);
    float* mv48  = (float*)alloc((size_t)N48 * 4);
    float* vfA48 = (float*)alloc((size_t)3 * N48 * 4);
    float* vfB48 = (float*)alloc((size_t)3 * N48 * 4);
    float* wrp48 = (float*)alloc((size_t)N48 * 4);
    float* vfA96 = (float*)alloc((size_t)3 * N96 * 4);
    float* vfB96 = (float*)alloc((size_t)3 * N96 * 4);
    float* vfC96 = (float*)alloc((size_t)3 * N96 * 4);
    float* wrp96 = (float*)alloc((size_t)N96 * 4);
    short* xin8  = (short*)alloc((size_t)8 * N96 * 2);
    short* y1    = (short*)alloc((size_t)32 * N96 * 2);
    short* y2    = (short*)alloc((size_t)64 * N96 * 2);
    short* wr1   = (short*)alloc((size_t)7168 * 2);
    short* wr2   = (short*)alloc((size_t)55296 * 2);
    short* wr3   = (short*)alloc((size_t)55296 * 2);
    short* wr4   = (short*)alloc((size_t)27648 * 2);
    float* part  = (float*)alloc((size_t)64 * 2304 * 2 * 4);
    float* stats = (float*)alloc((size_t)64 * 2 * 4);

    const int B = 256;
    const int g48  = (N48 + B - 1) / B;
    const int g96  = (N96 + B - 1) / B;
    const int g96c = (3 * N96 + B - 1) / B;

    // ---- all weight reorders (one launch) ----
    k_wreorder_all<<<(145408 + 255) / 256, B, 0, stream>>>(w1, w2, w3, w4, wr1, wr2, wr3, wr4);

    // ---- Level 0 (48^3) ----
    k_downsample2x<<<g48, B, 0, stream>>>(image, f48);
    k_downsample2x<<<g48, B, 0, stream>>>(moving, mv48);
    hipMemsetAsync(vfA48, 0, (size_t)3 * N48 * 4, stream);
    float* cur = vfA48; float* oth = vfB48;
    for (int it = 0; it < 2; ++it) {
        k_warp<<<g48, B, 0, stream>>>(mv48, cur, wrp48, D48);
        k_forces<<<g48, B, 0, stream>>>(wrp48, f48, mask, spacing, cur, D48, D96, 2.0f);
        k_smooth3<<<dim3(27, 3), B, 0, stream>>>(cur, oth, D48);
        float* tmp = cur; cur = oth; oth = tmp;
    }

    // ---- Level 1 (96^3) ----
    k_upsample_vf<<<g96c, B, 0, stream>>>(cur, vfA96);
    float* cur9 = vfA96; float* oth9 = vfB96;
    for (int it = 0; it < 2; ++it) {
        k_warp<<<g96, B, 0, stream>>>(moving, cur9, wrp96, D96);
        k_forces<<<g96, B, 0, stream>>>(wrp96, image, mask, spacing, cur9, D96, D96, 2.0f);
        k_smooth3<<<dim3(216, 3), B, 0, stream>>>(cur9, oth9, D96);
        float* tmp = cur9; cur9 = oth9; oth9 = tmp;
    }
    // cur9 == vfA96 here (final vf)

    // ---- CNN ----
    k_warp<<<g96, B, 0, stream>>>(moving, cur9, wrp96, D96);
    k_pack_cl<<<g96, B, 0, stream>>>(cur9, image, mask, wrp96, xin8);

    // conv1: 8(5)->32, full-tile, stats fused
    k_conv_v2<8, 32, 5, 32, false, true, false><<<2304, B, 0, stream>>>(
        xin8, wr1, y1, nullptr, nullptr, nullptr, part);
    k_stats_reduce<<<32, B, 0, stream>>>(part, stats, 2304, N96);

    // conv2: 32->64, norm+mish fused on input, stats fused on output
    k_conv_v2<32, 64, 32, 64, true, true, false><<<2304, B, 0, stream>>>(
        y1, wr2, y2, nullptr, nullptr, stats, part);
    k_stats_reduce<<<64, B, 0, stream>>>(part, stats, 2304, N96);

    // conv3: 64->32 (output reuses y1)
    k_conv_v2<64, 32, 64, 32, true, true, false><<<2304, B, 0, stream>>>(
        y2, wr3, y1, nullptr, nullptr, stats, part);
    k_stats_reduce<<<32, B, 0, stream>>>(part, stats, 2304, N96);

    // conv4: 32->3 (+bias), f32 channel-first output
    k_conv_v2<32, 32, 32, 3, true, false, true><<<2304, B, 0, stream>>>(
        y1, wr4, nullptr, vfC96, b4, stats, nullptr);

    // corrected_vf = smooth3d(vf + correction) -> straight to d_out; also emit vf output
    k_add3copy<<<g96c, B, 0, stream>>>(vfC96, cur9, out + (size_t)4 * N96);
    k_smooth3<<<dim3(216, 3), B, 0, stream>>>(vfC96, out + N96, D96);

    // corrected_warped_moving
    k_warp<<<g96, B, 0, stream>>>(moving, out + N96, out, D96);
}

// Round 5
// 809.875 us; speedup vs baseline: 7.2836x; 1.1123x over previous
//
#include <hip/hip_runtime.h>
#include <hip/hip_bf16.h>
#include <math.h>

#define DEV __device__ __forceinline__

constexpr int D96 = 96;
constexpr int N96 = D96 * D96 * D96;      // 884736
constexpr int D48 = 48;
constexpr int N48 = D48 * D48 * D48;      // 110592

// Gaussian kernel (sigma=1, radius=3), normalized
#define GW0 0.3990502796524549f
#define GW1 0.2420362293761143f
#define GW2 0.05400558262251696f
#define GW3 0.004433048175243745f

typedef __attribute__((ext_vector_type(8))) short s16x8;
typedef __attribute__((ext_vector_type(4))) short s16x4;
typedef __attribute__((ext_vector_type(4))) float f32x4;
typedef __attribute__((ext_vector_type(16))) float f32x16;

DEV int clampi(int v, int lo, int hi) { return v < lo ? lo : (v > hi ? hi : v); }

DEV short f2bf(float f) { __hip_bfloat16 h = __float2bfloat16(f); short s; __builtin_memcpy(&s, &h, 2); return s; }
DEV float bf2f(short s) { __hip_bfloat16 h; __builtin_memcpy(&h, &s, 2); return __bfloat162float(h); }

// ---------------- resize 96 -> 48, trilinear antialias (4-tap 1,3,3,1 /8, edge renorm)
__global__ void k_downsample2x(const float* __restrict__ src, float* __restrict__ dst)
{
    int idx = blockIdx.x * blockDim.x + threadIdx.x;
    if (idx >= N48) return;
    int x = idx % D48, y = (idx / D48) % D48, z = idx / (D48 * D48);

    float wz[4], wy[4], wx[4];
    int jz[4], jy[4], jx[4];
    auto mk = [](int i, float* w, int* j) {
        const float base[4] = {0.125f, 0.375f, 0.375f, 0.125f};
        float s = 0.f;
        #pragma unroll
        for (int t = 0; t < 4; ++t) {
            int jj = 2 * i - 1 + t;
            bool v = (jj >= 0) && (jj < D96);
            j[t] = v ? jj : 0;
            w[t] = v ? base[t] : 0.f;
            s += w[t];
        }
        float inv = 1.f / s;
        #pragma unroll
        for (int t = 0; t < 4; ++t) w[t] *= inv;
    };
    mk(z, wz, jz); mk(y, wy, jy); mk(x, wx, jx);

    float acc = 0.f;
    #pragma unroll
    for (int a = 0; a < 4; ++a) {
        #pragma unroll
        for (int b = 0; b < 4; ++b) {
            float wab = wz[a] * wy[b];
            int rowoff = (jz[a] * D96 + jy[b]) * D96;
            #pragma unroll
            for (int c = 0; c < 4; ++c)
                acc += wab * wx[c] * src[rowoff + jx[c]];
        }
    }
    dst[idx] = acc;
}

// ---------------- vf upsample 48 -> 96 (trilinear, edge renorm) with *2 magnitude scale
__global__ void k_upsample_vf(const float* __restrict__ src, float* __restrict__ dst)
{
    int idx = blockIdx.x * blockDim.x + threadIdx.x;
    if (idx >= 3 * N96) return;
    int c = idx / N96;
    int s = idx - c * N96;
    int x = s % D96, y = (s / D96) % D96, z = s / (D96 * D96);

    auto mk = [](int i, int* j, float* w) {
        int k = i >> 1;
        if ((i & 1) == 0) { j[0] = k - 1; w[0] = 0.25f; j[1] = k; w[1] = 0.75f; }
        else              { j[0] = k;     w[0] = 0.75f; j[1] = k + 1; w[1] = 0.25f; }
        float sum = 0.f;
        #pragma unroll
        for (int t = 0; t < 2; ++t) {
            bool v = (j[t] >= 0) && (j[t] < D48);
            if (!v) { w[t] = 0.f; j[t] = 0; }
            sum += w[t];
        }
        float inv = 1.f / sum;
        w[0] *= inv; w[1] *= inv;
    };
    int jz[2], jy[2], jx[2]; float wz[2], wy[2], wx[2];
    mk(z, jz, wz); mk(y, jy, wy); mk(x, jx, wx);

    const float* p = src + (size_t)c * N48;
    float acc = 0.f;
    #pragma unroll
    for (int a = 0; a < 2; ++a)
        #pragma unroll
        for (int b = 0; b < 2; ++b) {
            float wab = wz[a] * wy[b];
            int rowoff = (jz[a] * D48 + jy[b]) * D48;
            acc += wab * (wx[0] * p[rowoff + jx[0]] + wx[1] * p[rowoff + jx[1]]);
        }
    dst[idx] = 2.f * acc;   // per-axis magnitude scale 96/48
}

// ---------------- trilinear warp, mode='nearest' (clamped indices)
__global__ void k_warp(const float* __restrict__ img, const float* __restrict__ vf,
                       float* __restrict__ out, int D)
{
    int N = D * D * D;
    int idx = blockIdx.x * blockDim.x + threadIdx.x;
    if (idx >= N) return;
    int x = idx % D, y = (idx / D) % D, z = idx / (D * D);
    float cz = z + vf[idx], cy = y + vf[N + idx], cx = x + vf[2 * N + idx];
    float fz = floorf(cz), fy = floorf(cy), fx = floorf(cx);
    float wz = cz - fz, wy = cy - fy, wx = cx - fx;
    int z0 = clampi((int)fz, 0, D - 1), z1 = clampi((int)fz + 1, 0, D - 1);
    int y0 = clampi((int)fy, 0, D - 1), y1 = clampi((int)fy + 1, 0, D - 1);
    int x0 = clampi((int)fx, 0, D - 1), x1 = clampi((int)fx + 1, 0, D - 1);
    float v000 = img[(z0 * D + y0) * D + x0], v001 = img[(z0 * D + y0) * D + x1];
    float v010 = img[(z0 * D + y1) * D + x0], v011 = img[(z0 * D + y1) * D + x1];
    float v100 = img[(z1 * D + y0) * D + x0], v101 = img[(z1 * D + y0) * D + x1];
    float v110 = img[(z1 * D + y1) * D + x0], v111 = img[(z1 * D + y1) * D + x1];
    float c00 = v000 + wx * (v001 - v000);
    float c01 = v010 + wx * (v011 - v010);
    float c10 = v100 + wx * (v101 - v100);
    float c11 = v110 + wx * (v111 - v110);
    float c0 = c00 + wy * (c01 - c00);
    float c1 = c10 + wy * (c11 - c10);
    out[idx] = c0 + wz * (c1 - c0);
}

// ---------------- demon forces + vf update (in place)
__global__ void k_forces(const float* __restrict__ warped, const float* __restrict__ fixed,
                         const float* __restrict__ mask, const float* __restrict__ spacing,
                         float* __restrict__ vf, int D, int maskD, float tau)
{
    int N = D * D * D;
    int idx = blockIdx.x * blockDim.x + threadIdx.x;
    if (idx >= N) return;
    int x = idx % D, y = (idx / D) % D, z = idx / (D * D);
    float w0 = warped[idx];
    float diff = w0 - fixed[idx];
    int sZ = D * D, sY = D;
    float gz = (z == 0) ? warped[idx + sZ] - w0 : (z == D - 1) ? w0 - warped[idx - sZ]
               : 0.5f * (warped[idx + sZ] - warped[idx - sZ]);
    float gy = (y == 0) ? warped[idx + sY] - w0 : (y == D - 1) ? w0 - warped[idx - sY]
               : 0.5f * (warped[idx + sY] - warped[idx - sY]);
    float gx = (x == 0) ? warped[idx + 1] - w0 : (x == D - 1) ? w0 - warped[idx - 1]
               : 0.5f * (warped[idx + 1] - warped[idx - 1]);
    gz /= spacing[0]; gy /= spacing[1]; gx /= spacing[2];
    float denom = gz * gz + gy * gy + gx * gx + diff * diff;
    float m;
    if (D == maskD) m = mask[idx];
    else {
        float r = (float)maskD / (float)D;
        int mz = clampi((int)((z + 0.5f) * r), 0, maskD - 1);
        int my = clampi((int)((y + 0.5f) * r), 0, maskD - 1);
        int mx = clampi((int)((x + 0.5f) * r), 0, maskD - 1);
        m = mask[(mz * maskD + my) * maskD + mx];
    }
    if (denom > 1e-9f) {
        float sc = tau * diff / denom * m;
        vf[idx]         += sc * gz;
        vf[N + idx]     += sc * gy;
        vf[2 * N + idx] += sc * gx;
    }
}

// ---------------- fused 3-axis separable 7-tap Gaussian, zero pad; 16^3 tile, 22^3 halo
__global__ __launch_bounds__(256, 2)
void k_smooth3(const float* __restrict__ src, float* __restrict__ dst, int D)
{
    __shared__ float B1[10648];       // 22^3 staged input
    __shared__ float B2[7744];        // 16*22*22 after z-pass
    float* B3 = B1;                   // 16*16*22 after y-pass (overlays dead B1)
    int nt = D >> 4;
    int b = blockIdx.x;
    int tx = b % nt, ty = (b / nt) % nt, tz = b / (nt * nt);
    int c = blockIdx.y;
    int N = D * D * D;
    const float* s = src + (size_t)c * N;
    float* d = dst + (size_t)c * N;
    int x0 = tx * 16, y0 = ty * 16, z0 = tz * 16;
    int tid = threadIdx.x;

    for (int l = tid; l < 10648; l += 256) {
        int xx = l % 22, yy = (l / 22) % 22, zz = l / 484;
        int gz = z0 + zz - 3, gy = y0 + yy - 3, gx = x0 + xx - 3;
        float v = 0.f;
        if ((unsigned)gz < (unsigned)D && (unsigned)gy < (unsigned)D && (unsigned)gx < (unsigned)D)
            v = s[((size_t)gz * D + gy) * D + gx];
        B1[l] = v;
    }
    __syncthreads();
    for (int l = tid; l < 16 * 484; l += 256) {
        int xx = l % 22, yy = (l / 22) % 22, zo = l / 484;
        int base = (zo + 3) * 484 + yy * 22 + xx;
        B2[l] = GW0 * B1[base]
              + GW1 * (B1[base - 484] + B1[base + 484])
              + GW2 * (B1[base - 968] + B1[base + 968])
              + GW3 * (B1[base - 1452] + B1[base + 1452]);
    }
    __syncthreads();
    for (int l = tid; l < 16 * 16 * 22; l += 256) {
        int xx = l % 22, yo = (l / 22) % 16, zo = l / 352;
        int base = zo * 484 + (yo + 3) * 22 + xx;
        B3[l] = GW0 * B2[base]
              + GW1 * (B2[base - 22] + B2[base + 22])
              + GW2 * (B2[base - 44] + B2[base + 44])
              + GW3 * (B2[base - 66] + B2[base + 66]);
    }
    __syncthreads();
    for (int l = tid; l < 4096; l += 256) {
        int xo = l % 16, yo = (l / 16) % 16, zo = l / 256;
        int base = zo * 352 + yo * 22 + xo + 3;
        float a = GW0 * B3[base]
                + GW1 * (B3[base - 1] + B3[base + 1])
                + GW2 * (B3[base - 2] + B3[base + 2])
                + GW3 * (B3[base - 3] + B3[base + 3]);
        d[((size_t)(z0 + zo) * D + (y0 + yo)) * D + (x0 + xo)] = a;
    }
}

// ---------------- pack CNN input channels-last bf16: [vox][8] = {vf0,vf1,vf2,img*mask,warped,0,0,0}
__global__ void k_pack_cl(const float* __restrict__ vf, const float* __restrict__ image,
                          const float* __restrict__ mask, const float* __restrict__ warped,
                          short* __restrict__ xin8)
{
    int i = blockIdx.x * blockDim.x + threadIdx.x;
    if (i >= N96) return;
    s16x8 v;
    v[0] = f2bf(vf[i]); v[1] = f2bf(vf[N96 + i]); v[2] = f2bf(vf[2 * N96 + i]);
    v[3] = f2bf(image[i] * mask[i]); v[4] = f2bf(warped[i]);
    v[5] = 0; v[6] = 0; v[7] = 0;
    *reinterpret_cast<s16x8*>(&xin8[(size_t)i * 8]) = v;
}

// ---------------- all weight reorders in one launch.
// Layout: Wr[kg][COUTP][8] bf16, k = kg*8+j, (off,ci) = (k/CINP, k%CINP), off = dz*9+dy*3+dx
__global__ void k_wreorder_all(const float* __restrict__ w1, const float* __restrict__ w2,
                               const float* __restrict__ w3, const float* __restrict__ w4,
                               short* __restrict__ r1, short* __restrict__ r2,
                               short* __restrict__ r3, short* __restrict__ r4)
{
    int i = blockIdx.x * 256 + threadIdx.x;
    const int S1 = 7168, S2 = 55296, S3 = 55296, S4 = 13824;
    const float* w; short* r; int CIN, CINP, COUT, COUTP;
    int idx = i;
    if (idx < S1)              { w = w1; r = r1; CIN = 5;  CINP = 8;  COUT = 32; COUTP = 32; }
    else if ((idx -= S1) < S2) { w = w2; r = r2; CIN = 32; CINP = 32; COUT = 64; COUTP = 64; }
    else if ((idx -= S2) < S3) { w = w3; r = r3; CIN = 64; CINP = 64; COUT = 32; COUTP = 32; }
    else if ((idx -= S3) < S4) { w = w4; r = r4; CIN = 32; CINP = 32; COUT = 3;  COUTP = 16; }
    else return;
    int j = idx & 7;
    int co = (idx >> 3) % COUTP;
    int kg = idx / (8 * COUTP);
    int k = kg * 8 + j;
    int off = k / CINP, ci = k % CINP;
    float v = 0.f;
    if (co < COUT && off < 27 && ci < CIN)
        v = w[((size_t)co * CIN + ci) * 27 + off];
    r[idx] = f2bf(v);
}

// fast mish: x * tanh(softplus(x)) == x - 2x / ((1+e^x)^2 + 1)
DEV float mishf(float f)
{
    float e = __expf(f);
    float t = 1.f + e;
    float u = t * t + 1.f;
    return f - 2.f * f * __builtin_amdgcn_rcpf(u);
}

// ---------------- conv1 only: 8ch input, full 3-plane tile, 32x32x16 MFMA, fused stats
__global__ __launch_bounds__(256, 4)
void k_conv1(const short* __restrict__ act, const short* __restrict__ Wr,
             short* __restrict__ outcl, float* __restrict__ part)
{
    constexpr int YH = 6, TN = 3, KS = 14;       // (27*8+15)/16
    constexpr int TILE_G = 3 * YH * 98;          // granules (G=1)
    __shared__ __align__(16) short tile[TILE_G * 8];
    float* red = (float*)tile;

    int b = blockIdx.x;
    int xcd = b & 7, bidx = b >> 3;
    int zblk = xcd * 12 + bidx / 24;
    int y0 = (bidx % 24) * 4;

    int tid = threadIdx.x;
    int lane = tid & 63, wave = tid >> 6;
    int ln31 = lane & 31, hi = lane >> 5;

    for (int i = tid; i < TILE_G; i += 256) {
        int xi = i % 98, yi = (i / 98) % YH, zi = i / (98 * YH);
        int gz = zblk + zi - 1, gy = y0 + yi - 1, gx = xi - 1;
        s16x8 v = {0, 0, 0, 0, 0, 0, 0, 0};
        if ((unsigned)gz < 96u && (unsigned)gy < 96u && (unsigned)gx < 96u)
            v = *reinterpret_cast<const s16x8*>(&act[(size_t)((gz * 96 + gy) * 96 + gx) * 8]);
        *reinterpret_cast<s16x8*>(&tile[i * 8]) = v;
    }
    __syncthreads();

    f32x16 acc[TN];
    #pragma unroll
    for (int i = 0; i < TN; ++i)
        #pragma unroll
        for (int e = 0; e < 16; ++e) acc[i][e] = 0.f;

    int xb_[TN];
    #pragma unroll
    for (int i = 0; i < TN; ++i) xb_[i] = i * 32 + ln31;

    #pragma unroll
    for (int ks = 0; ks < KS; ++ks) {
        s16x8 a = *reinterpret_cast<const s16x8*>(&Wr[((size_t)(ks * 2 + hi) * 32 + ln31) * 8]);
        int off = ks * 2 + hi; if (off > 26) off = 26;   // padded k: weights are 0
        int dz = off / 9, r9 = off - dz * 9, dy = r9 / 3, dx = r9 - dy * 3;
        #pragma unroll
        for (int i = 0; i < TN; ++i) {
            int gi = (dz * YH + wave + dy) * 98 + xb_[i] + dx;
            s16x8 bf = *reinterpret_cast<const s16x8*>(&tile[gi * 8]);
            acc[i] = __builtin_amdgcn_mfma_f32_32x32x16_bf16(a, bf, acc[i], 0, 0, 0);
        }
    }

    // epilogue + stats (COUTP=32, TM=1)
    float st_s[16], st_q[16];
    #pragma unroll
    for (int j = 0; j < 16; ++j) { st_s[j] = 0.f; st_q[j] = 0.f; }
    #pragma unroll
    for (int i = 0; i < TN; ++i) {
        int vox = ((zblk * 96) + y0 + wave) * 96 + xb_[i];
        #pragma unroll
        for (int q = 0; q < 4; ++q) {
            s16x4 pk;
            #pragma unroll
            for (int r = 0; r < 4; ++r) {
                float v = acc[i][q * 4 + r];
                st_s[q * 4 + r] += v; st_q[q * 4 + r] += v * v;
                pk[r] = f2bf(v);
            }
            *reinterpret_cast<s16x4*>(&outcl[(size_t)vox * 32 + q * 8 + hi * 4]) = pk;
        }
    }
    #pragma unroll
    for (int j = 0; j < 16; ++j) {
        #pragma unroll
        for (int o = 1; o <= 16; o <<= 1) {
            st_s[j] += __shfl_xor(st_s[j], o);
            st_q[j] += __shfl_xor(st_q[j], o);
        }
    }
    __syncthreads();
    if (ln31 == 0) {
        int base = (wave * 2 + hi) * 16;
        #pragma unroll
        for (int j = 0; j < 16; ++j) {
            red[(base + j) * 2]     = st_s[j];
            red[(base + j) * 2 + 1] = st_q[j];
        }
    }
    __syncthreads();
    if (tid < 64) {
        int c = tid >> 1, sel = tid & 1;
        int q = (c >> 3) & 3, hic = (c >> 2) & 1, r = c & 3;
        int j = q * 4 + r;
        float v = 0.f;
        #pragma unroll
        for (int w = 0; w < 4; ++w)
            v += red[((w * 2 + hic) * 16 + j) * 2 + sel];
        part[((size_t)c * gridDim.x + blockIdx.x) * 2 + sel] = v;
    }
}

// ---------------- conv2/conv3: chunked 32-cin staging, 32x32x16 MFMA, fully unrolled K
// A = weights [cout x K], B = input patches [K x vox], D[cout][vox].
template <int CINP, int COUTP, int MINW>
__global__ __launch_bounds__(256, MINW)
void k_conv_v3(const short* __restrict__ act, const short* __restrict__ Wr,
               short* __restrict__ outcl, float* __restrict__ part)
{
    constexpr int G = CINP / 8;               // global granules per voxel
    constexpr int HALVES = CINP / 32;
    constexpr int TM = COUTP / 32;
    constexpr int TN = 3;
    constexpr int YH = 6;
    __shared__ __align__(16) short tile[YH * 98 * 32];   // 37632 B
    float* red = (float*)tile;

    int b = blockIdx.x;
    int xcd = b & 7, bidx = b >> 3;           // XCD z-slab swizzle
    int zblk = xcd * 12 + bidx / 24;
    int y0 = (bidx % 24) * 4;

    int tid = threadIdx.x;
    int lane = tid & 63, wave = tid >> 6;
    int ln31 = lane & 31, hi = lane >> 5;

    int xb_[TN];
    #pragma unroll
    for (int i = 0; i < TN; ++i) xb_[i] = i * 32 + ln31;

    f32x16 acc[TN][TM];
    #pragma unroll
    for (int i = 0; i < TN; ++i)
        #pragma unroll
        for (int m = 0; m < TM; ++m)
            #pragma unroll
            for (int e = 0; e < 16; ++e) acc[i][m][e] = 0.f;

    for (int p = 0; p < 3; ++p) {
        int gz = zblk + p - 1;
        for (int h = 0; h < HALVES; ++h) {
            __syncthreads();                  // previous tile reads done
            for (int i = tid; i < YH * 98 * 4; i += 256) {
                int g = i & 3, xi = (i >> 2) % 98, yi = (i >> 2) / 98;
                int gy = y0 + yi - 1, gx = xi - 1;
                s16x8 v = {0, 0, 0, 0, 0, 0, 0, 0};
                if ((unsigned)gz < 96u && (unsigned)gy < 96u && (unsigned)gx < 96u)
                    v = *reinterpret_cast<const s16x8*>(
                        &act[(size_t)((gz * 96 + gy) * 96 + gx) * CINP + (h * 4 + g) * 8]);
                int slot = g ^ ((xi >> 1) & 3);
                *reinterpret_cast<s16x8*>(&tile[(((yi * 98 + xi) << 2) + slot) * 8]) = v;
            }
            __syncthreads();
            int kgbase = p * 9 * G + h * 4;
            #pragma unroll
            for (int ks = 0; ks < 18; ++ks) {
                int kg = kgbase + (ks >> 1) * G + (ks & 1) * 2 + hi;
                s16x8 A[TM];
                #pragma unroll
                for (int m = 0; m < TM; ++m)
                    A[m] = *reinterpret_cast<const s16x8*>(
                        &Wr[((size_t)kg * COUTP + m * 32 + ln31) * 8]);
                int dy = (ks >> 1) / 3, dx = (ks >> 1) % 3;
                int gl = (ks & 1) * 2 + hi;
                #pragma unroll
                for (int i = 0; i < TN; ++i) {
                    int xi = xb_[i] + dx;
                    int gi = (((wave + dy) * 98 + xi) << 2) + (gl ^ ((xi >> 1) & 3));
                    s16x8 bf = *reinterpret_cast<const s16x8*>(&tile[gi * 8]);
                    #pragma unroll
                    for (int m = 0; m < TM; ++m)
                        acc[i][m] = __builtin_amdgcn_mfma_f32_32x32x16_bf16(A[m], bf, acc[i][m], 0, 0, 0);
                }
            }
        }
    }

    // epilogue: D col = vox = ln31, row(c) = (reg&3) + 8*(reg>>2) + 4*hi (+32m); fused stats
    float st_s[TM * 16], st_q[TM * 16];
    #pragma unroll
    for (int j = 0; j < TM * 16; ++j) { st_s[j] = 0.f; st_q[j] = 0.f; }

    #pragma unroll
    for (int i = 0; i < TN; ++i) {
        int vox = ((zblk * 96) + y0 + wave) * 96 + xb_[i];
        #pragma unroll
        for (int m = 0; m < TM; ++m) {
            #pragma unroll
            for (int q = 0; q < 4; ++q) {
                s16x4 pk;
                #pragma unroll
                for (int r = 0; r < 4; ++r) {
                    float v = acc[i][m][q * 4 + r];
                    st_s[m * 16 + q * 4 + r] += v;
                    st_q[m * 16 + q * 4 + r] += v * v;
                    pk[r] = f2bf(v);
                }
                *reinterpret_cast<s16x4*>(&outcl[(size_t)vox * COUTP + m * 32 + q * 8 + hi * 4]) = pk;
            }
        }
    }

    #pragma unroll
    for (int j = 0; j < TM * 16; ++j) {
        #pragma unroll
        for (int o = 1; o <= 16; o <<= 1) {
            st_s[j] += __shfl_xor(st_s[j], o);
            st_q[j] += __shfl_xor(st_q[j], o);
        }
    }
    __syncthreads();
    if (ln31 == 0) {
        int base = (wave * 2 + hi) * (TM * 16);
        #pragma unroll
        for (int j = 0; j < TM * 16; ++j) {
            red[(base + j) * 2]     = st_s[j];
            red[(base + j) * 2 + 1] = st_q[j];
        }
    }
    __syncthreads();
    if (tid < COUTP * 2) {
        int c = tid >> 1, sel = tid & 1;
        int m = c >> 5, q = (c >> 3) & 3, hic = (c >> 2) & 1, r = c & 3;
        int j = m * 16 + q * 4 + r;
        float v = 0.f;
        #pragma unroll
        for (int w = 0; w < 4; ++w)
            v += red[((w * 2 + hic) * (TM * 16) + j) * 2 + sel];
        part[((size_t)c * gridDim.x + blockIdx.x) * 2 + sel] = v;
    }
}

// ---------------- conv4: 32->3 via 16x16x32 MFMA (COUTP=16), fused vf-add + vf copy
__global__ __launch_bounds__(256, 4)
void k_conv4(const short* __restrict__ act, const short* __restrict__ Wr,
             const float* __restrict__ bias, const float* __restrict__ vf,
             float* __restrict__ corr, float* __restrict__ outvf)
{
    constexpr int YH = 6;
    __shared__ __align__(16) short tile[YH * 98 * 32];

    int b = blockIdx.x;
    int xcd = b & 7, bidx = b >> 3;
    int zblk = xcd * 12 + bidx / 24;
    int y0 = (bidx % 24) * 4;

    int tid = threadIdx.x;
    int lane = tid & 63, wave = tid >> 6;
    int ln15 = lane & 15, lg = lane >> 4;

    f32x4 acc[6];
    #pragma unroll
    for (int i = 0; i < 6; ++i) acc[i] = {0.f, 0.f, 0.f, 0.f};

    for (int p = 0; p < 3; ++p) {
        int gz = zblk + p - 1;
        __syncthreads();
        for (int i = tid; i < YH * 98 * 4; i += 256) {
            int g = i & 3, xi = (i >> 2) % 98, yi = (i >> 2) / 98;
            int gy = y0 + yi - 1, gx = xi - 1;
            s16x8 v = {0, 0, 0, 0, 0, 0, 0, 0};
            if ((unsigned)gz < 96u && (unsigned)gy < 96u && (unsigned)gx < 96u)
                v = *reinterpret_cast<const s16x8*>(
                    &act[(size_t)((gz * 96 + gy) * 96 + gx) * 32 + g * 8]);
            int slot = g ^ ((xi >> 1) & 3);
            *reinterpret_cast<s16x8*>(&tile[(((yi * 98 + xi) << 2) + slot) * 8]) = v;
        }
        __syncthreads();
        #pragma unroll
        for (int ks = 0; ks < 9; ++ks) {
            int kg = (p * 9 + ks) * 4 + lg;
            s16x8 a = *reinterpret_cast<const s16x8*>(&Wr[((size_t)kg * 16 + ln15) * 8]);
            int dy = ks / 3, dx = ks % 3;
            #pragma unroll
            for (int i = 0; i < 6; ++i) {
                int xi = i * 16 + ln15 + dx;
                int gi = (((wave + dy) * 98 + xi) << 2) + (lg ^ ((xi >> 1) & 3));
                s16x8 bf = *reinterpret_cast<const s16x8*>(&tile[gi * 8]);
                acc[i] = __builtin_amdgcn_mfma_f32_16x16x32_bf16(a, bf, acc[i], 0, 0, 0);
            }
        }
    }
    // D: col=ln15 (vox), row = lg*4 + r (cout). Rows 0..2 live on lg==0.
    if (lg == 0) {
        #pragma unroll
        for (int i = 0; i < 6; ++i) {
            int vox = ((zblk * 96) + y0 + wave) * 96 + i * 16 + ln15;
            #pragma unroll
            for (int r = 0; r < 3; ++r) {
                float v = vf[(size_t)r * N96 + vox];
                corr[(size_t)r * N96 + vox] = acc[i][r] + bias[r] + v;
                outvf[(size_t)r * N96 + vox] = v;
            }
        }
    }
}

// ---------------- instance-norm apply + mish, channels-last, in place
template <int C>
__global__ void k_norm_mish_cl(short* __restrict__ x, const float* __restrict__ stats)
{
    constexpr int G8 = C / 8;
    int gt = blockIdx.x * 256 + threadIdx.x;
    int cg = threadIdx.x % G8;       // fixed per thread (stride divisible by G8)
    float mean[8], inv[8];
    #pragma unroll
    for (int j = 0; j < 8; ++j) { mean[j] = stats[2 * (cg * 8 + j)]; inv[j] = stats[2 * (cg * 8 + j) + 1]; }
    const int TGn = N96 * G8;
    int stride = gridDim.x * 256;
    for (int i = gt; i < TGn; i += stride) {
        s16x8 v = *reinterpret_cast<const s16x8*>(&x[(size_t)i * 8]);
        #pragma unroll
        for (int j = 0; j < 8; ++j)
            v[j] = f2bf(mishf((bf2f(v[j]) - mean[j]) * inv[j]));
        *reinterpret_cast<s16x8*>(&x[(size_t)i * 8]) = v;
    }
}

// stage 2: reduce per-block partials/channel -> mean + inv_std
__global__ void k_stats_reduce(const float* __restrict__ part, float* __restrict__ stats,
                               int G, int N)
{
    int c = blockIdx.x;
    int t = threadIdx.x;
    float s = 0.f, s2 = 0.f;
    for (int i = t; i < G; i += blockDim.x) {
        s  += part[((size_t)c * G + i) * 2];
        s2 += part[((size_t)c * G + i) * 2 + 1];
    }
    #pragma unroll
    for (int o = 32; o > 0; o >>= 1) { s += __shfl_down(s, o); s2 += __shfl_down(s2, o); }
    __shared__ float a[4], b[4];
    int lane = t & 63, wid = t >> 6;
    if (lane == 0) { a[wid] = s; b[wid] = s2; }
    __syncthreads();
    if (t == 0) {
        float ss = a[0] + a[1] + a[2] + a[3];
        float qq = b[0] + b[1] + b[2] + b[3];
        float mean = ss / (float)N;
        float var = qq / (float)N - mean * mean;
        stats[2 * c] = mean;
        stats[2 * c + 1] = rsqrtf(var + 1e-5f);
    }
}

extern "C" void kernel_launch(void* const* d_in, const int* in_sizes, int n_in,
                              void* d_out, int out_size, void* d_ws, size_t ws_size,
                              hipStream_t stream)
{
    const float* image   = (const float*)d_in[0];
    const float* mask    = (const float*)d_in[1];
    const float* moving  = (const float*)d_in[2];
    const float* spacing = (const float*)d_in[3];
    const float* w1 = (const float*)d_in[4];
    const float* w2 = (const float*)d_in[5];
    const float* w3 = (const float*)d_in[6];
    const float* w4 = (const float*)d_in[7];
    const float* b4 = (const float*)d_in[8];
    float* out = (float*)d_out;

    char* ws = (char*)d_ws;
    size_t off = 0;
    auto alloc = [&](size_t bytes) -> char* {
        char* p = ws + off;
        off += (bytes + 255) & ~(size_t)255;
        return p;
    };
    float* f48   = (float*)alloc((size_t)N48 * 4);
    float* mv48  = (float*)alloc((size_t)N48 * 4);
    float* vfA48 = (float*)alloc((size_t)3 * N48 * 4);
    float* vfB48 = (float*)alloc((size_t)3 * N48 * 4);
    float* wrp48 = (float*)alloc((size_t)N48 * 4);
    float* vfA96 = (float*)alloc((size_t)3 * N96 * 4);
    float* vfB96 = (float*)alloc((size_t)3 * N96 * 4);
    float* vfC96 = (float*)alloc((size_t)3 * N96 * 4);
    float* wrp96 = (float*)alloc((size_t)N96 * 4);
    short* xin8  = (short*)alloc((size_t)8 * N96 * 2);
    short* y1    = (short*)alloc((size_t)32 * N96 * 2);
    short* y2    = (short*)alloc((size_t)64 * N96 * 2);
    short* wr1   = (short*)alloc((size_t)7168 * 2);
    short* wr2   = (short*)alloc((size_t)55296 * 2);
    short* wr3   = (short*)alloc((size_t)55296 * 2);
    short* wr4   = (short*)alloc((size_t)13824 * 2);
    float* part  = (float*)alloc((size_t)64 * 2304 * 2 * 4);
    float* stats = (float*)alloc((size_t)64 * 2 * 4);

    const int B = 256;
    const int g48  = (N48 + B - 1) / B;
    const int g96  = (N96 + B - 1) / B;
    const int g96c = (3 * N96 + B - 1) / B;

    // ---- all weight reorders (one launch) ----
    k_wreorder_all<<<(131584 + 255) / 256, B, 0, stream>>>(w1, w2, w3, w4, wr1, wr2, wr3, wr4);

    // ---- Level 0 (48^3) ----
    k_downsample2x<<<g48, B, 0, stream>>>(image, f48);
    k_downsample2x<<<g48, B, 0, stream>>>(moving, mv48);
    hipMemsetAsync(vfA48, 0, (size_t)3 * N48 * 4, stream);
    float* cur = vfA48; float* oth = vfB48;
    for (int it = 0; it < 2; ++it) {
        k_warp<<<g48, B, 0, stream>>>(mv48, cur, wrp48, D48);
        k_forces<<<g48, B, 0, stream>>>(wrp48, f48, mask, spacing, cur, D48, D96, 2.0f);
        k_smooth3<<<dim3(27, 3), B, 0, stream>>>(cur, oth, D48);
        float* tmp = cur; cur = oth; oth = tmp;
    }

    // ---- Level 1 (96^3) ----
    k_upsample_vf<<<g96c, B, 0, stream>>>(cur, vfA96);
    float* cur9 = vfA96; float* oth9 = vfB96;
    for (int it = 0; it < 2; ++it) {
        k_warp<<<g96, B, 0, stream>>>(moving, cur9, wrp96, D96);
        k_forces<<<g96, B, 0, stream>>>(wrp96, image, mask, spacing, cur9, D96, D96, 2.0f);
        k_smooth3<<<dim3(216, 3), B, 0, stream>>>(cur9, oth9, D96);
        float* tmp = cur9; cur9 = oth9; oth9 = tmp;
    }
    // cur9 == vfA96 here (final vf)

    // ---- CNN ----
    k_warp<<<g96, B, 0, stream>>>(moving, cur9, wrp96, D96);
    k_pack_cl<<<g96, B, 0, stream>>>(cur9, image, mask, wrp96, xin8);

    // conv1: 8(5)->32, stats fused; then reduce + norm
    k_conv1<<<2304, B, 0, stream>>>(xin8, wr1, y1, part);
    k_stats_reduce<<<32, B, 0, stream>>>(part, stats, 2304, N96);
    k_norm_mish_cl<32><<<2048, B, 0, stream>>>(y1, stats);

    // conv2: 32->64
    k_conv_v3<32, 64, 3><<<2304, B, 0, stream>>>(y1, wr2, y2, part);
    k_stats_reduce<<<64, B, 0, stream>>>(part, stats, 2304, N96);
    k_norm_mish_cl<64><<<2048, B, 0, stream>>>(y2, stats);

    // conv3: 64->32 (output reuses y1)
    k_conv_v3<64, 32, 4><<<2304, B, 0, stream>>>(y2, wr3, y1, part);
    k_stats_reduce<<<32, B, 0, stream>>>(part, stats, 2304, N96);
    k_norm_mish_cl<32><<<2048, B, 0, stream>>>(y1, stats);

    // conv4: 32->3 (+bias), f32 out = correction + vf; also emits vf output copy
    k_conv4<<<2304, B, 0, stream>>>(y1, wr4, b4, cur9, vfC96, out + (size_t)4 * N96);

    // corrected_vf = smooth3d(vf + correction) -> straight to d_out
    k_smooth3<<<dim3(216, 3), B, 0, stream>>>(vfC96, out + N96, D96);

    // corrected_warped_moving
    k_warp<<<g96, B, 0, stream>>>(moving, out + N96, out, D96);
}

// Round 6
// 806.841 us; speedup vs baseline: 7.3110x; 1.0038x over previous
//
#include <hip/hip_runtime.h>
#include <hip/hip_bf16.h>
#include <math.h>

#define DEV __device__ __forceinline__

constexpr int D96 = 96;
constexpr int N96 = D96 * D96 * D96;      // 884736
constexpr int D48 = 48;
constexpr int N48 = D48 * D48 * D48;      // 110592

// Gaussian kernel (sigma=1, radius=3), normalized
#define GW0 0.3990502796524549f
#define GW1 0.2420362293761143f
#define GW2 0.05400558262251696f
#define GW3 0.004433048175243745f

typedef __attribute__((ext_vector_type(8))) short s16x8;
typedef __attribute__((ext_vector_type(4))) short s16x4;
typedef __attribute__((ext_vector_type(4))) float f32x4;
typedef __attribute__((ext_vector_type(16))) float f32x16;

DEV int clampi(int v, int lo, int hi) { return v < lo ? lo : (v > hi ? hi : v); }

DEV short f2bf(float f) { __hip_bfloat16 h = __float2bfloat16(f); short s; __builtin_memcpy(&s, &h, 2); return s; }
DEV float bf2f(short s) { __hip_bfloat16 h; __builtin_memcpy(&h, &s, 2); return __bfloat162float(h); }

// ---------------- resize 96 -> 48, trilinear antialias (4-tap 1,3,3,1 /8, edge renorm)
__global__ void k_downsample2x(const float* __restrict__ src, float* __restrict__ dst)
{
    int idx = blockIdx.x * blockDim.x + threadIdx.x;
    if (idx >= N48) return;
    int x = idx % D48, y = (idx / D48) % D48, z = idx / (D48 * D48);

    float wz[4], wy[4], wx[4];
    int jz[4], jy[4], jx[4];
    auto mk = [](int i, float* w, int* j) {
        const float base[4] = {0.125f, 0.375f, 0.375f, 0.125f};
        float s = 0.f;
        #pragma unroll
        for (int t = 0; t < 4; ++t) {
            int jj = 2 * i - 1 + t;
            bool v = (jj >= 0) && (jj < D96);
            j[t] = v ? jj : 0;
            w[t] = v ? base[t] : 0.f;
            s += w[t];
        }
        float inv = 1.f / s;
        #pragma unroll
        for (int t = 0; t < 4; ++t) w[t] *= inv;
    };
    mk(z, wz, jz); mk(y, wy, jy); mk(x, wx, jx);

    float acc = 0.f;
    #pragma unroll
    for (int a = 0; a < 4; ++a) {
        #pragma unroll
        for (int b = 0; b < 4; ++b) {
            float wab = wz[a] * wy[b];
            int rowoff = (jz[a] * D96 + jy[b]) * D96;
            #pragma unroll
            for (int c = 0; c < 4; ++c)
                acc += wab * wx[c] * src[rowoff + jx[c]];
        }
    }
    dst[idx] = acc;
}

// ---------------- vf upsample 48 -> 96 (trilinear, edge renorm) with *2 magnitude scale
__global__ void k_upsample_vf(const float* __restrict__ src, float* __restrict__ dst)
{
    int idx = blockIdx.x * blockDim.x + threadIdx.x;
    if (idx >= 3 * N96) return;
    int c = idx / N96;
    int s = idx - c * N96;
    int x = s % D96, y = (s / D96) % D96, z = s / (D96 * D96);

    auto mk = [](int i, int* j, float* w) {
        int k = i >> 1;
        if ((i & 1) == 0) { j[0] = k - 1; w[0] = 0.25f; j[1] = k; w[1] = 0.75f; }
        else              { j[0] = k;     w[0] = 0.75f; j[1] = k + 1; w[1] = 0.25f; }
        float sum = 0.f;
        #pragma unroll
        for (int t = 0; t < 2; ++t) {
            bool v = (j[t] >= 0) && (j[t] < D48);
            if (!v) { w[t] = 0.f; j[t] = 0; }
            sum += w[t];
        }
        float inv = 1.f / sum;
        w[0] *= inv; w[1] *= inv;
    };
    int jz[2], jy[2], jx[2]; float wz[2], wy[2], wx[2];
    mk(z, jz, wz); mk(y, jy, wy); mk(x, jx, wx);

    const float* p = src + (size_t)c * N48;
    float acc = 0.f;
    #pragma unroll
    for (int a = 0; a < 2; ++a)
        #pragma unroll
        for (int b = 0; b < 2; ++b) {
            float wab = wz[a] * wy[b];
            int rowoff = (jz[a] * D48 + jy[b]) * D48;
            acc += wab * (wx[0] * p[rowoff + jx[0]] + wx[1] * p[rowoff + jx[1]]);
        }
    dst[idx] = 2.f * acc;   // per-axis magnitude scale 96/48
}

// ---------------- trilinear warp, mode='nearest' (clamped indices)
__global__ void k_warp(const float* __restrict__ img, const float* __restrict__ vf,
                       float* __restrict__ out, int D)
{
    int N = D * D * D;
    int idx = blockIdx.x * blockDim.x + threadIdx.x;
    if (idx >= N) return;
    int x = idx % D, y = (idx / D) % D, z = idx / (D * D);
    float cz = z + vf[idx], cy = y + vf[N + idx], cx = x + vf[2 * N + idx];
    float fz = floorf(cz), fy = floorf(cy), fx = floorf(cx);
    float wz = cz - fz, wy = cy - fy, wx = cx - fx;
    int z0 = clampi((int)fz, 0, D - 1), z1 = clampi((int)fz + 1, 0, D - 1);
    int y0 = clampi((int)fy, 0, D - 1), y1 = clampi((int)fy + 1, 0, D - 1);
    int x0 = clampi((int)fx, 0, D - 1), x1 = clampi((int)fx + 1, 0, D - 1);
    float v000 = img[(z0 * D + y0) * D + x0], v001 = img[(z0 * D + y0) * D + x1];
    float v010 = img[(z0 * D + y1) * D + x0], v011 = img[(z0 * D + y1) * D + x1];
    float v100 = img[(z1 * D + y0) * D + x0], v101 = img[(z1 * D + y0) * D + x1];
    float v110 = img[(z1 * D + y1) * D + x0], v111 = img[(z1 * D + y1) * D + x1];
    float c00 = v000 + wx * (v001 - v000);
    float c01 = v010 + wx * (v011 - v010);
    float c10 = v100 + wx * (v101 - v100);
    float c11 = v110 + wx * (v111 - v110);
    float c0 = c00 + wy * (c01 - c00);
    float c1 = c10 + wy * (c11 - c10);
    out[idx] = c0 + wz * (c1 - c0);
}

// ---------------- demon forces + vf update (in place)
__global__ void k_forces(const float* __restrict__ warped, const float* __restrict__ fixed,
                         const float* __restrict__ mask, const float* __restrict__ spacing,
                         float* __restrict__ vf, int D, int maskD, float tau)
{
    int N = D * D * D;
    int idx = blockIdx.x * blockDim.x + threadIdx.x;
    if (idx >= N) return;
    int x = idx % D, y = (idx / D) % D, z = idx / (D * D);
    float w0 = warped[idx];
    float diff = w0 - fixed[idx];
    int sZ = D * D, sY = D;
    float gz = (z == 0) ? warped[idx + sZ] - w0 : (z == D - 1) ? w0 - warped[idx - sZ]
               : 0.5f * (warped[idx + sZ] - warped[idx - sZ]);
    float gy = (y == 0) ? warped[idx + sY] - w0 : (y == D - 1) ? w0 - warped[idx - sY]
               : 0.5f * (warped[idx + sY] - warped[idx - sY]);
    float gx = (x == 0) ? warped[idx + 1] - w0 : (x == D - 1) ? w0 - warped[idx - 1]
               : 0.5f * (warped[idx + 1] - warped[idx - 1]);
    gz /= spacing[0]; gy /= spacing[1]; gx /= spacing[2];
    float denom = gz * gz + gy * gy + gx * gx + diff * diff;
    float m;
    if (D == maskD) m = mask[idx];
    else {
        float r = (float)maskD / (float)D;
        int mz = clampi((int)((z + 0.5f) * r), 0, maskD - 1);
        int my = clampi((int)((y + 0.5f) * r), 0, maskD - 1);
        int mx = clampi((int)((x + 0.5f) * r), 0, maskD - 1);
        m = mask[(mz * maskD + my) * maskD + mx];
    }
    if (denom > 1e-9f) {
        float sc = tau * diff / denom * m;
        vf[idx]         += sc * gz;
        vf[N + idx]     += sc * gy;
        vf[2 * N + idx] += sc * gx;
    }
}

// ---------------- fused 3-axis separable 7-tap Gaussian, zero pad; 16^3 tile, 22^3 halo
__global__ __launch_bounds__(256, 2)
void k_smooth3(const float* __restrict__ src, float* __restrict__ dst, int D)
{
    __shared__ float B1[10648];       // 22^3 staged input
    __shared__ float B2[7744];        // 16*22*22 after z-pass
    float* B3 = B1;                   // 16*16*22 after y-pass (overlays dead B1)
    int nt = D >> 4;
    int b = blockIdx.x;
    int tx = b % nt, ty = (b / nt) % nt, tz = b / (nt * nt);
    int c = blockIdx.y;
    int N = D * D * D;
    const float* s = src + (size_t)c * N;
    float* d = dst + (size_t)c * N;
    int x0 = tx * 16, y0 = ty * 16, z0 = tz * 16;
    int tid = threadIdx.x;

    for (int l = tid; l < 10648; l += 256) {
        int xx = l % 22, yy = (l / 22) % 22, zz = l / 484;
        int gz = z0 + zz - 3, gy = y0 + yy - 3, gx = x0 + xx - 3;
        float v = 0.f;
        if ((unsigned)gz < (unsigned)D && (unsigned)gy < (unsigned)D && (unsigned)gx < (unsigned)D)
            v = s[((size_t)gz * D + gy) * D + gx];
        B1[l] = v;
    }
    __syncthreads();
    for (int l = tid; l < 16 * 484; l += 256) {
        int xx = l % 22, yy = (l / 22) % 22, zo = l / 484;
        int base = (zo + 3) * 484 + yy * 22 + xx;
        B2[l] = GW0 * B1[base]
              + GW1 * (B1[base - 484] + B1[base + 484])
              + GW2 * (B1[base - 968] + B1[base + 968])
              + GW3 * (B1[base - 1452] + B1[base + 1452]);
    }
    __syncthreads();
    for (int l = tid; l < 16 * 16 * 22; l += 256) {
        int xx = l % 22, yo = (l / 22) % 16, zo = l / 352;
        int base = zo * 484 + (yo + 3) * 22 + xx;
        B3[l] = GW0 * B2[base]
              + GW1 * (B2[base - 22] + B2[base + 22])
              + GW2 * (B2[base - 44] + B2[base + 44])
              + GW3 * (B2[base - 66] + B2[base + 66]);
    }
    __syncthreads();
    for (int l = tid; l < 4096; l += 256) {
        int xo = l % 16, yo = (l / 16) % 16, zo = l / 256;
        int base = zo * 352 + yo * 22 + xo + 3;
        float a = GW0 * B3[base]
                + GW1 * (B3[base - 1] + B3[base + 1])
                + GW2 * (B3[base - 2] + B3[base + 2])
                + GW3 * (B3[base - 3] + B3[base + 3]);
        d[((size_t)(z0 + zo) * D + (y0 + yo)) * D + (x0 + xo)] = a;
    }
}

// ---------------- pack CNN input channels-last bf16: [vox][8] = {vf0,vf1,vf2,img*mask,warped,0,0,0}
__global__ void k_pack_cl(const float* __restrict__ vf, const float* __restrict__ image,
                          const float* __restrict__ mask, const float* __restrict__ warped,
                          short* __restrict__ xin8)
{
    int i = blockIdx.x * blockDim.x + threadIdx.x;
    if (i >= N96) return;
    s16x8 v;
    v[0] = f2bf(vf[i]); v[1] = f2bf(vf[N96 + i]); v[2] = f2bf(vf[2 * N96 + i]);
    v[3] = f2bf(image[i] * mask[i]); v[4] = f2bf(warped[i]);
    v[5] = 0; v[6] = 0; v[7] = 0;
    *reinterpret_cast<s16x8*>(&xin8[(size_t)i * 8]) = v;
}

// ---------------- all weight reorders in one launch.
// Layout: Wr[kg][COUTP][8] bf16, k = kg*8+j, (off,ci) = (k/CINP, k%CINP), off = dz*9+dy*3+dx
__global__ void k_wreorder_all(const float* __restrict__ w1, const float* __restrict__ w2,
                               const float* __restrict__ w3, const float* __restrict__ w4,
                               short* __restrict__ r1, short* __restrict__ r2,
                               short* __restrict__ r3, short* __restrict__ r4)
{
    int i = blockIdx.x * 256 + threadIdx.x;
    const int S1 = 7168, S2 = 55296, S3 = 55296, S4 = 13824;
    const float* w; short* r; int CIN, CINP, COUT, COUTP;
    int idx = i;
    if (idx < S1)              { w = w1; r = r1; CIN = 5;  CINP = 8;  COUT = 32; COUTP = 32; }
    else if ((idx -= S1) < S2) { w = w2; r = r2; CIN = 32; CINP = 32; COUT = 64; COUTP = 64; }
    else if ((idx -= S2) < S3) { w = w3; r = r3; CIN = 64; CINP = 64; COUT = 32; COUTP = 32; }
    else if ((idx -= S3) < S4) { w = w4; r = r4; CIN = 32; CINP = 32; COUT = 3;  COUTP = 16; }
    else return;
    int j = idx & 7;
    int co = (idx >> 3) % COUTP;
    int kg = idx / (8 * COUTP);
    int k = kg * 8 + j;
    int off = k / CINP, ci = k % CINP;
    float v = 0.f;
    if (co < COUT && off < 27 && ci < CIN)
        v = w[((size_t)co * CIN + ci) * 27 + off];
    r[idx] = f2bf(v);
}

// fast mish: x * tanh(softplus(x)) == x - 2x / ((1+e^x)^2 + 1)
DEV float mishf(float f)
{
    float e = __expf(f);
    float t = 1.f + e;
    float u = t * t + 1.f;
    return f - 2.f * f * __builtin_amdgcn_rcpf(u);
}

// ---------------- conv1 only: 8ch input, full 3-plane tile, 32x32x16 MFMA, fused stats,
// LDS-transpose epilogue for coalesced channels-last stores
__global__ __launch_bounds__(256, 4)
void k_conv1(const short* __restrict__ act, const short* __restrict__ Wr,
             short* __restrict__ outcl, float* __restrict__ part)
{
    constexpr int YH = 6, TN = 3, KS = 14;       // (27*8+15)/16
    constexpr int TILE_G = 3 * YH * 98;          // granules (G=1) -> 14112 shorts
    __shared__ __align__(16) short tile[TILE_G * 8];   // 28224 B (>= transpose 24576 B)
    float* red = (float*)tile;

    int b = blockIdx.x;
    int xcd = b & 7, bidx = b >> 3;
    int zblk = xcd * 12 + bidx / 24;
    int y0 = (bidx % 24) * 4;

    int tid = threadIdx.x;
    int lane = tid & 63, wave = tid >> 6;
    int ln31 = lane & 31, hi = lane >> 5;

    for (int i = tid; i < TILE_G; i += 256) {
        int xi = i % 98, yi = (i / 98) % YH, zi = i / (98 * YH);
        int gz = zblk + zi - 1, gy = y0 + yi - 1, gx = xi - 1;
        s16x8 v = {0, 0, 0, 0, 0, 0, 0, 0};
        if ((unsigned)gz < 96u && (unsigned)gy < 96u && (unsigned)gx < 96u)
            v = *reinterpret_cast<const s16x8*>(&act[(size_t)((gz * 96 + gy) * 96 + gx) * 8]);
        *reinterpret_cast<s16x8*>(&tile[i * 8]) = v;
    }
    __syncthreads();

    f32x16 acc[TN];
    #pragma unroll
    for (int i = 0; i < TN; ++i)
        #pragma unroll
        for (int e = 0; e < 16; ++e) acc[i][e] = 0.f;

    int xb_[TN];
    #pragma unroll
    for (int i = 0; i < TN; ++i) xb_[i] = i * 32 + ln31;

    #pragma unroll
    for (int ks = 0; ks < KS; ++ks) {
        s16x8 a = *reinterpret_cast<const s16x8*>(&Wr[((size_t)(ks * 2 + hi) * 32 + ln31) * 8]);
        int off = ks * 2 + hi; if (off > 26) off = 26;   // padded k: weights are 0
        int dz = off / 9, r9 = off - dz * 9, dy = r9 / 3, dx = r9 - dy * 3;
        #pragma unroll
        for (int i = 0; i < TN; ++i) {
            int gi = (dz * YH + wave + dy) * 98 + xb_[i] + dx;
            s16x8 bf = *reinterpret_cast<const s16x8*>(&tile[gi * 8]);
            acc[i] = __builtin_amdgcn_mfma_f32_32x32x16_bf16(a, bf, acc[i], 0, 0, 0);
        }
    }

    // stats (shfl over ln31)
    float st_s[16], st_q[16];
    #pragma unroll
    for (int j = 0; j < 16; ++j) { st_s[j] = 0.f; st_q[j] = 0.f; }
    #pragma unroll
    for (int i = 0; i < TN; ++i)
        #pragma unroll
        for (int e = 0; e < 16; ++e) {
            float v = acc[i][e];
            st_s[e] += v; st_q[e] += v * v;
        }
    #pragma unroll
    for (int j = 0; j < 16; ++j) {
        #pragma unroll
        for (int o = 1; o <= 16; o <<= 1) {
            st_s[j] += __shfl_xor(st_s[j], o);
            st_q[j] += __shfl_xor(st_q[j], o);
        }
    }

    // transpose epilogue: acc -> LDS [row][x][ch] (swizzled) -> coalesced stores
    __syncthreads();
    #pragma unroll
    for (int i = 0; i < TN; ++i) {
        int x = xb_[i];
        #pragma unroll
        for (int q = 0; q < 4; ++q) {
            s16x4 pk;
            #pragma unroll
            for (int r = 0; r < 4; ++r) pk[r] = f2bf(acc[i][q * 4 + r]);
            int bo = (((wave * 96 + x) * 32 + q * 8 + hi * 4) * 2) ^ ((x & 3) << 4);
            *reinterpret_cast<s16x4*>((char*)tile + bo) = pk;
        }
    }
    __syncthreads();
    for (int t = tid; t < 4 * 96 * 4; t += 256) {
        int gran = t & 3;
        int x = (t >> 2) % 96;
        int row = t / (4 * 96);
        int bo = (((row * 96 + x) * 32) * 2 + gran * 16) ^ ((x & 3) << 4);
        s16x8 v = *reinterpret_cast<const s16x8*>((char*)tile + bo);
        int vox = ((zblk * 96) + y0 + row) * 96 + x;
        *reinterpret_cast<s16x8*>(&outcl[(size_t)vox * 32 + gran * 8]) = v;
    }

    // block-level stats reduce via LDS overlay
    __syncthreads();
    if (ln31 == 0) {
        int base = (wave * 2 + hi) * 16;
        #pragma unroll
        for (int j = 0; j < 16; ++j) {
            red[(base + j) * 2]     = st_s[j];
            red[(base + j) * 2 + 1] = st_q[j];
        }
    }
    __syncthreads();
    if (tid < 64) {
        int c = tid >> 1, sel = tid & 1;
        int q = (c >> 3) & 3, hic = (c >> 2) & 1, r = c & 3;
        int j = q * 4 + r;
        float v = 0.f;
        #pragma unroll
        for (int w = 0; w < 4; ++w)
            v += red[((w * 2 + hic) * 16 + j) * 2 + sel];
        part[((size_t)c * gridDim.x + blockIdx.x) * 2 + sel] = v;
    }
}

// ---------------- conv2/conv3: chunked 32-cin staging, 32x32x16 MFMA, fully unrolled K,
// LDS-transpose epilogue for coalesced channels-last stores
template <int CINP, int COUTP, int MINW>
__global__ __launch_bounds__(256, MINW)
void k_conv_v3(const short* __restrict__ act, const short* __restrict__ Wr,
               short* __restrict__ outcl, float* __restrict__ part)
{
    constexpr int G = CINP / 8;               // global granules per voxel
    constexpr int HALVES = CINP / 32;
    constexpr int TM = COUTP / 32;
    constexpr int TN = 3;
    constexpr int YH = 6;
    constexpr int TILE_SH = YH * 98 * 32;     // 18816 shorts
    constexpr int TR_SH = 4 * 96 * COUTP;     // transpose buffer shorts
    constexpr int SH_SIZE = TILE_SH > TR_SH ? TILE_SH : TR_SH;
    __shared__ __align__(16) short tile[SH_SIZE];
    float* red = (float*)tile;

    int b = blockIdx.x;
    int xcd = b & 7, bidx = b >> 3;           // XCD z-slab swizzle
    int zblk = xcd * 12 + bidx / 24;
    int y0 = (bidx % 24) * 4;

    int tid = threadIdx.x;
    int lane = tid & 63, wave = tid >> 6;
    int ln31 = lane & 31, hi = lane >> 5;

    int xb_[TN];
    #pragma unroll
    for (int i = 0; i < TN; ++i) xb_[i] = i * 32 + ln31;

    f32x16 acc[TN][TM];
    #pragma unroll
    for (int i = 0; i < TN; ++i)
        #pragma unroll
        for (int m = 0; m < TM; ++m)
            #pragma unroll
            for (int e = 0; e < 16; ++e) acc[i][m][e] = 0.f;

    for (int p = 0; p < 3; ++p) {
        int gz = zblk + p - 1;
        for (int h = 0; h < HALVES; ++h) {
            __syncthreads();                  // previous tile reads done
            for (int i = tid; i < YH * 98 * 4; i += 256) {
                int g = i & 3, xi = (i >> 2) % 98, yi = (i >> 2) / 98;
                int gy = y0 + yi - 1, gx = xi - 1;
                s16x8 v = {0, 0, 0, 0, 0, 0, 0, 0};
                if ((unsigned)gz < 96u && (unsigned)gy < 96u && (unsigned)gx < 96u)
                    v = *reinterpret_cast<const s16x8*>(
                        &act[(size_t)((gz * 96 + gy) * 96 + gx) * CINP + (h * 4 + g) * 8]);
                int slot = g ^ ((xi >> 1) & 3);
                *reinterpret_cast<s16x8*>(&tile[(((yi * 98 + xi) << 2) + slot) * 8]) = v;
            }
            __syncthreads();
            int kgbase = p * 9 * G + h * 4;
            #pragma unroll
            for (int ks = 0; ks < 18; ++ks) {
                int kg = kgbase + (ks >> 1) * G + (ks & 1) * 2 + hi;
                s16x8 A[TM];
                #pragma unroll
                for (int m = 0; m < TM; ++m)
                    A[m] = *reinterpret_cast<const s16x8*>(
                        &Wr[((size_t)kg * COUTP + m * 32 + ln31) * 8]);
                int dy = (ks >> 1) / 3, dx = (ks >> 1) % 3;
                int gl = (ks & 1) * 2 + hi;
                #pragma unroll
                for (int i = 0; i < TN; ++i) {
                    int xi = xb_[i] + dx;
                    int gi = (((wave + dy) * 98 + xi) << 2) + (gl ^ ((xi >> 1) & 3));
                    s16x8 bf = *reinterpret_cast<const s16x8*>(&tile[gi * 8]);
                    #pragma unroll
                    for (int m = 0; m < TM; ++m)
                        acc[i][m] = __builtin_amdgcn_mfma_f32_32x32x16_bf16(A[m], bf, acc[i][m], 0, 0, 0);
                }
            }
        }
    }

    // stats (shfl over ln31); channel of acc[.][m][e] = (e&3) + 8*(e>>2) + 4*hi + 32m
    float st_s[TM * 16], st_q[TM * 16];
    #pragma unroll
    for (int j = 0; j < TM * 16; ++j) { st_s[j] = 0.f; st_q[j] = 0.f; }
    #pragma unroll
    for (int i = 0; i < TN; ++i)
        #pragma unroll
        for (int m = 0; m < TM; ++m)
            #pragma unroll
            for (int e = 0; e < 16; ++e) {
                float v = acc[i][m][e];
                st_s[m * 16 + e] += v;
                st_q[m * 16 + e] += v * v;
            }
    #pragma unroll
    for (int j = 0; j < TM * 16; ++j) {
        #pragma unroll
        for (int o = 1; o <= 16; o <<= 1) {
            st_s[j] += __shfl_xor(st_s[j], o);
            st_q[j] += __shfl_xor(st_q[j], o);
        }
    }

    // transpose epilogue: acc -> LDS [row][x][ch] (16B-granule XOR swizzle) -> coalesced stores
    constexpr int XM = (COUTP == 64) ? 7 : 3;
    __syncthreads();
    #pragma unroll
    for (int i = 0; i < TN; ++i) {
        int x = xb_[i];
        #pragma unroll
        for (int m = 0; m < TM; ++m)
            #pragma unroll
            for (int q = 0; q < 4; ++q) {
                s16x4 pk;
                #pragma unroll
                for (int r = 0; r < 4; ++r) pk[r] = f2bf(acc[i][m][q * 4 + r]);
                int bo = (((wave * 96 + x) * COUTP + m * 32 + q * 8 + hi * 4) * 2) ^ ((x & XM) << 4);
                *reinterpret_cast<s16x4*>((char*)tile + bo) = pk;
            }
    }
    __syncthreads();
    constexpr int GR = COUTP / 8;
    for (int t = tid; t < 4 * 96 * GR; t += 256) {
        int gran = t % GR;
        int x = (t / GR) % 96;
        int row = t / (GR * 96);
        int bo = (((row * 96 + x) * COUTP) * 2 + gran * 16) ^ ((x & XM) << 4);
        s16x8 v = *reinterpret_cast<const s16x8*>((char*)tile + bo);
        int vox = ((zblk * 96) + y0 + row) * 96 + x;
        *reinterpret_cast<s16x8*>(&outcl[(size_t)vox * COUTP + gran * 8]) = v;
    }

    // block-level stats reduce via LDS overlay
    __syncthreads();
    if (ln31 == 0) {
        int base = (wave * 2 + hi) * (TM * 16);
        #pragma unroll
        for (int j = 0; j < TM * 16; ++j) {
            red[(base + j) * 2]     = st_s[j];
            red[(base + j) * 2 + 1] = st_q[j];
        }
    }
    __syncthreads();
    if (tid < COUTP * 2) {
        int c = tid >> 1, sel = tid & 1;
        int m = c >> 5, q = (c >> 3) & 3, hic = (c >> 2) & 1, r = c & 3;
        int j = m * 16 + q * 4 + r;
        float v = 0.f;
        #pragma unroll
        for (int w = 0; w < 4; ++w)
            v += red[((w * 2 + hic) * (TM * 16) + j) * 2 + sel];
        part[((size_t)c * gridDim.x + blockIdx.x) * 2 + sel] = v;
    }
}

// ---------------- conv4: 32->3 via 16x16x32 MFMA (COUTP=16), fused vf-add + vf copy
__global__ __launch_bounds__(256, 4)
void k_conv4(const short* __restrict__ act, const short* __restrict__ Wr,
             const float* __restrict__ bias, const float* __restrict__ vf,
             float* __restrict__ corr, float* __restrict__ outvf)
{
    constexpr int YH = 6;
    __shared__ __align__(16) short tile[YH * 98 * 32];

    int b = blockIdx.x;
    int xcd = b & 7, bidx = b >> 3;
    int zblk = xcd * 12 + bidx / 24;
    int y0 = (bidx % 24) * 4;

    int tid = threadIdx.x;
    int lane = tid & 63, wave = tid >> 6;
    int ln15 = lane & 15, lg = lane >> 4;

    f32x4 acc[6];
    #pragma unroll
    for (int i = 0; i < 6; ++i) acc[i] = {0.f, 0.f, 0.f, 0.f};

    for (int p = 0; p < 3; ++p) {
        int gz = zblk + p - 1;
        __syncthreads();
        for (int i = tid; i < YH * 98 * 4; i += 256) {
            int g = i & 3, xi = (i >> 2) % 98, yi = (i >> 2) / 98;
            int gy = y0 + yi - 1, gx = xi - 1;
            s16x8 v = {0, 0, 0, 0, 0, 0, 0, 0};
            if ((unsigned)gz < 96u && (unsigned)gy < 96u && (unsigned)gx < 96u)
                v = *reinterpret_cast<const s16x8*>(
                    &act[(size_t)((gz * 96 + gy) * 96 + gx) * 32 + g * 8]);
            int slot = g ^ ((xi >> 1) & 3);
            *reinterpret_cast<s16x8*>(&tile[(((yi * 98 + xi) << 2) + slot) * 8]) = v;
        }
        __syncthreads();
        #pragma unroll
        for (int ks = 0; ks < 9; ++ks) {
            int kg = (p * 9 + ks) * 4 + lg;
            s16x8 a = *reinterpret_cast<const s16x8*>(&Wr[((size_t)kg * 16 + ln15) * 8]);
            int dy = ks / 3, dx = ks % 3;
            #pragma unroll
            for (int i = 0; i < 6; ++i) {
                int xi = i * 16 + ln15 + dx;
                int gi = (((wave + dy) * 98 + xi) << 2) + (lg ^ ((xi >> 1) & 3));
                s16x8 bf = *reinterpret_cast<const s16x8*>(&tile[gi * 8]);
                acc[i] = __builtin_amdgcn_mfma_f32_16x16x32_bf16(a, bf, acc[i], 0, 0, 0);
            }
        }
    }
    // D: col=ln15 (vox), row = lg*4 + r (cout). Rows 0..2 live on lg==0.
    if (lg == 0) {
        #pragma unroll
        for (int i = 0; i < 6; ++i) {
            int vox = ((zblk * 96) + y0 + wave) * 96 + i * 16 + ln15;
            #pragma unroll
            for (int r = 0; r < 3; ++r) {
                float v = vf[(size_t)r * N96 + vox];
                corr[(size_t)r * N96 + vox] = acc[i][r] + bias[r] + v;
                outvf[(size_t)r * N96 + vox] = v;
            }
        }
    }
}

// ---------------- instance-norm apply + mish, channels-last, in place
template <int C>
__global__ void k_norm_mish_cl(short* __restrict__ x, const float* __restrict__ stats)
{
    constexpr int G8 = C / 8;
    int gt = blockIdx.x * 256 + threadIdx.x;
    int cg = threadIdx.x % G8;       // fixed per thread (stride divisible by G8)
    float mean[8], inv[8];
    #pragma unroll
    for (int j = 0; j < 8; ++j) { mean[j] = stats[2 * (cg * 8 + j)]; inv[j] = stats[2 * (cg * 8 + j) + 1]; }
    const int TGn = N96 * G8;
    int stride = gridDim.x * 256;
    for (int i = gt; i < TGn; i += stride) {
        s16x8 v = *reinterpret_cast<const s16x8*>(&x[(size_t)i * 8]);
        #pragma unroll
        for (int j = 0; j < 8; ++j)
            v[j] = f2bf(mishf((bf2f(v[j]) - mean[j]) * inv[j]));
        *reinterpret_cast<s16x8*>(&x[(size_t)i * 8]) = v;
    }
}

// stage 2: reduce per-block partials/channel -> mean + inv_std
__global__ void k_stats_reduce(const float* __restrict__ part, float* __restrict__ stats,
                               int G, int N)
{
    int c = blockIdx.x;
    int t = threadIdx.x;
    float s = 0.f, s2 = 0.f;
    for (int i = t; i < G; i += blockDim.x) {
        s  += part[((size_t)c * G + i) * 2];
        s2 += part[((size_t)c * G + i) * 2 + 1];
    }
    #pragma unroll
    for (int o = 32; o > 0; o >>= 1) { s += __shfl_down(s, o); s2 += __shfl_down(s2, o); }
    __shared__ float a[4], b[4];
    int lane = t & 63, wid = t >> 6;
    if (lane == 0) { a[wid] = s; b[wid] = s2; }
    __syncthreads();
    if (t == 0) {
        float ss = a[0] + a[1] + a[2] + a[3];
        float qq = b[0] + b[1] + b[2] + b[3];
        float mean = ss / (float)N;
        float var = qq / (float)N - mean * mean;
        stats[2 * c] = mean;
        stats[2 * c + 1] = rsqrtf(var + 1e-5f);
    }
}

extern "C" void kernel_launch(void* const* d_in, const int* in_sizes, int n_in,
                              void* d_out, int out_size, void* d_ws, size_t ws_size,
                              hipStream_t stream)
{
    const float* image   = (const float*)d_in[0];
    const float* mask    = (const float*)d_in[1];
    const float* moving  = (const float*)d_in[2];
    const float* spacing = (const float*)d_in[3];
    const float* w1 = (const float*)d_in[4];
    const float* w2 = (const float*)d_in[5];
    const float* w3 = (const float*)d_in[6];
    const float* w4 = (const float*)d_in[7];
    const float* b4 = (const float*)d_in[8];
    float* out = (float*)d_out;

    char* ws = (char*)d_ws;
    size_t off = 0;
    auto alloc = [&](size_t bytes) -> char* {
        char* p = ws + off;
        off += (bytes + 255) & ~(size_t)255;
        return p;
    };
    float* f48   = (float*)alloc((size_t)N48 * 4);
    float* mv48  = (float*)alloc((size_t)N48 * 4);
    float* vfA48 = (float*)alloc((size_t)3 * N48 * 4);
    float* vfB48 = (float*)alloc((size_t)3 * N48 * 4);
    float* wrp48 = (float*)alloc((size_t)N48 * 4);
    float* vfA96 = (float*)alloc((size_t)3 * N96 * 4);
    float* vfB96 = (float*)alloc((size_t)3 * N96 * 4);
    float* vfC96 = (float*)alloc((size_t)3 * N96 * 4);
    float* wrp96 = (float*)alloc((size_t)N96 * 4);
    short* xin8  = (short*)alloc((size_t)8 * N96 * 2);
    short* y1    = (short*)alloc((size_t)32 * N96 * 2);
    short* y2    = (short*)alloc((size_t)64 * N96 * 2);
    short* wr1   = (short*)alloc((size_t)7168 * 2);
    short* wr2   = (short*)alloc((size_t)55296 * 2);
    short* wr3   = (short*)alloc((size_t)55296 * 2);
    short* wr4   = (short*)alloc((size_t)13824 * 2);
    float* part  = (float*)alloc((size_t)64 * 2304 * 2 * 4);
    float* stats = (float*)alloc((size_t)64 * 2 * 4);

    const int B = 256;
    const int g48  = (N48 + B - 1) / B;
    const int g96  = (N96 + B - 1) / B;
    const int g96c = (3 * N96 + B - 1) / B;

    // ---- all weight reorders (one launch) ----
    k_wreorder_all<<<(131584 + 255) / 256, B, 0, stream>>>(w1, w2, w3, w4, wr1, wr2, wr3, wr4);

    // ---- Level 0 (48^3) ----
    k_downsample2x<<<g48, B, 0, stream>>>(image, f48);
    k_downsample2x<<<g48, B, 0, stream>>>(moving, mv48);
    hipMemsetAsync(vfA48, 0, (size_t)3 * N48 * 4, stream);
    float* cur = vfA48; float* oth = vfB48;
    for (int it = 0; it < 2; ++it) {
        k_warp<<<g48, B, 0, stream>>>(mv48, cur, wrp48, D48);
        k_forces<<<g48, B, 0, stream>>>(wrp48, f48, mask, spacing, cur, D48, D96, 2.0f);
        k_smooth3<<<dim3(27, 3), B, 0, stream>>>(cur, oth, D48);
        float* tmp = cur; cur = oth; oth = tmp;
    }

    // ---- Level 1 (96^3) ----
    k_upsample_vf<<<g96c, B, 0, stream>>>(cur, vfA96);
    float* cur9 = vfA96; float* oth9 = vfB96;
    for (int it = 0; it < 2; ++it) {
        k_warp<<<g96, B, 0, stream>>>(moving, cur9, wrp96, D96);
        k_forces<<<g96, B, 0, stream>>>(wrp96, image, mask, spacing, cur9, D96, D96, 2.0f);
        k_smooth3<<<dim3(216, 3), B, 0, stream>>>(cur9, oth9, D96);
        float* tmp = cur9; cur9 = oth9; oth9 = tmp;
    }
    // cur9 == vfA96 here (final vf)

    // ---- CNN ----
    k_warp<<<g96, B, 0, stream>>>(moving, cur9, wrp96, D96);
    k_pack_cl<<<g96, B, 0, stream>>>(cur9, image, mask, wrp96, xin8);

    // conv1: 8(5)->32, stats fused; then reduce + norm
    k_conv1<<<2304, B, 0, stream>>>(xin8, wr1, y1, part);
    k_stats_reduce<<<32, B, 0, stream>>>(part, stats, 2304, N96);
    k_norm_mish_cl<32><<<2048, B, 0, stream>>>(y1, stats);

    // conv2: 32->64
    k_conv_v3<32, 64, 3><<<2304, B, 0, stream>>>(y1, wr2, y2, part);
    k_stats_reduce<<<64, B, 0, stream>>>(part, stats, 2304, N96);
    k_norm_mish_cl<64><<<2048, B, 0, stream>>>(y2, stats);

    // conv3: 64->32 (output reuses y1)
    k_conv_v3<64, 32, 4><<<2304, B, 0, stream>>>(y2, wr3, y1, part);
    k_stats_reduce<<<32, B, 0, stream>>>(part, stats, 2304, N96);
    k_norm_mish_cl<32><<<2048, B, 0, stream>>>(y1, stats);

    // conv4: 32->3 (+bias), f32 out = correction + vf; also emits vf output copy
    k_conv4<<<2304, B, 0, stream>>>(y1, wr4, b4, cur9, vfC96, out + (size_t)4 * N96);

    // corrected_vf = smooth3d(vf + correction) -> straight to d_out
    k_smooth3<<<dim3(216, 3), B, 0, stream>>>(vfC96, out + N96, D96);

    // corrected_warped_moving
    k_warp<<<g96, B, 0, stream>>>(moving, out + N96, out, D96);
}